// Round 1
// baseline (2666.938 us; speedup 1.0000x reference)
//
#include <hip/hip_runtime.h>
#include <hip/hip_bf16.h>
#include <math.h>

// Problem constants
#define BGR 8        // graphs
#define PP 4096      // points per graph
#define NPTS 32768   // B*P
#define KNN 20
#define LCOV 10
#define FF 32
#define KS 5
#define NCLS 40
#define NGROUP 24    // 3*B, rows of ys
#define GROUPLEN 131072  // P*F flat elements per group

// ---------------------------------------------------------------------------
// Kernel 1: brute-force KNN per graph. One block = 256 points of one graph.
// Maintains per-thread sorted top-20 (ascending distance, ties -> lower index)
// matching jax.lax.top_k(-d) semantics.
// ---------------------------------------------------------------------------
__global__ __launch_bounds__(256) void knn_kernel(const float* __restrict__ pos,
                                                  int* __restrict__ nbr) {
    __shared__ float sx[PP];
    __shared__ float sy[PP];
    __shared__ float sz[PP];
    int b = blockIdx.x >> 4;        // graph id (16 chunks per graph)
    int chunk = blockIdx.x & 15;
    const float* gp = pos + (size_t)b * PP * 3;
    for (int i = threadIdx.x; i < PP; i += 256) {
        sx[i] = gp[i * 3 + 0];
        sy[i] = gp[i * 3 + 1];
        sz[i] = gp[i * 3 + 2];
    }
    __syncthreads();

    int li = chunk * 256 + threadIdx.x;   // local point index in graph
    float px = sx[li], py = sy[li], pz = sz[li];

    float bd[KNN];
    int bi[KNN];
#pragma unroll
    for (int k = 0; k < KNN; k++) { bd[k] = INFINITY; bi[k] = -1; }
    float worst = INFINITY;

    for (int j = 0; j < PP; j++) {
        float dx = px - sx[j];
        float dy = py - sy[j];
        float dz = pz - sz[j];
        float d = dx * dx + dy * dy + dz * dz;
        if (j == li) continue;
        if (d < worst) {
            int k = KNN - 1;
            while (k > 0 && bd[k - 1] > d) {
                bd[k] = bd[k - 1];
                bi[k] = bi[k - 1];
                k--;
            }
            bd[k] = d;
            bi[k] = j;
            worst = bd[KNN - 1];
        }
    }

    int gi = b * PP + li;
#pragma unroll
    for (int k = 0; k < KNN; k++) nbr[gi * KNN + k] = b * PP + bi[k];
}

// ---------------------------------------------------------------------------
// 3x3 helpers + power iteration (replicates reference arithmetic)
// ---------------------------------------------------------------------------
__device__ inline void mat3vec(const float M[9], const float v[3], float w[3]) {
    w[0] = M[0] * v[0] + M[1] * v[1] + M[2] * v[2];
    w[1] = M[3] * v[0] + M[4] * v[1] + M[5] * v[2];
    w[2] = M[6] * v[0] + M[7] * v[1] + M[8] * v[2];
}

__device__ inline float pi3(const float M[9], float v[3]) {
    v[0] = v[1] = v[2] = 0.57735026918962576f;  // 3^-0.5 as f32
#pragma unroll
    for (int it = 0; it < 5; ++it) {
        float w[3];
        mat3vec(M, v, w);
        float nrm = sqrtf(w[0] * w[0] + w[1] * w[1] + w[2] * w[2]) + 1e-12f;
        v[0] = w[0] / nrm;
        v[1] = w[1] / nrm;
        v[2] = w[2] / nrm;
    }
    float w[3];
    mat3vec(M, v, w);
    return v[0] * w[0] + v[1] * w[1] + v[2] * w[2];
}

// ---------------------------------------------------------------------------
// Kernel 2: per-point cov -> eig -> dirc -> spline conv -> node features.
// Wsp staged in LDS transposed [f][flat] (stride 125) to spread LDS banks.
// ---------------------------------------------------------------------------
__global__ __launch_bounds__(256) void point_kernel(
    const float* __restrict__ pos, const int* __restrict__ nbr,
    const float* __restrict__ Wsp, const float* __restrict__ root,
    const float* __restrict__ bias, float* __restrict__ node,
    float* __restrict__ v3out) {
    __shared__ float sWt[FF * 125];  // [f][flat]
    for (int i = threadIdx.x; i < FF * 125; i += 256) {
        int f = i / 125;
        int j = i - f * 125;
        sWt[i] = Wsp[j * FF + f];
    }
    __syncthreads();

    int n = blockIdx.x * 256 + threadIdx.x;
    float px = pos[n * 3 + 0], py = pos[n * 3 + 1], pz = pos[n * 3 + 2];

    float cx[KNN], cy[KNN], cz[KNN];
#pragma unroll
    for (int k = 0; k < KNN; k++) {
        int id = nbr[n * KNN + k];
        cx[k] = pos[id * 3 + 0] - px;
        cy[k] = pos[id * 3 + 1] - py;
        cz[k] = pos[id * 3 + 2] - pz;
    }

    // covariance over the L nearest
    float M[9] = {0.f, 0.f, 0.f, 0.f, 0.f, 0.f, 0.f, 0.f, 0.f};
#pragma unroll
    for (int m = 0; m < LCOV; m++) {
        M[0] += cx[m] * cx[m];
        M[1] += cx[m] * cy[m];
        M[2] += cx[m] * cz[m];
        M[4] += cy[m] * cy[m];
        M[5] += cy[m] * cz[m];
        M[8] += cz[m] * cz[m];
    }
    M[3] = M[1];
    M[6] = M[2];
    M[7] = M[5];

    float v1[3], v2[3], v3[3];
    float l1 = pi3(M, v1);
    float M2[9];
#pragma unroll
    for (int c = 0; c < 3; c++)
#pragma unroll
        for (int d = 0; d < 3; d++) M2[c * 3 + d] = M[c * 3 + d] - l1 * v1[c] * v1[d];
    pi3(M2, v2);
    // v3 = normalize(cross(v1, v2))
    v3[0] = v1[1] * v2[2] - v1[2] * v2[1];
    v3[1] = v1[2] * v2[0] - v1[0] * v2[2];
    v3[2] = v1[0] * v2[1] - v1[1] * v2[0];
    {
        float nrm = sqrtf(v3[0] * v3[0] + v3[1] * v3[1] + v3[2] * v3[2]) + 1e-12f;
        v3[0] /= nrm;
        v3[1] /= nrm;
        v3[2] /= nrm;
    }

    // pass 1 over neighbors: sign accumulator + max_abs
    float ssum = 0.f, mx = 0.f;
#pragma unroll
    for (int k = 0; k < KNN; k++) {
        float d0 = cx[k] * v1[0] + cy[k] * v1[1] + cz[k] * v1[2];
        float d1 = cx[k] * v2[0] + cy[k] * v2[1] + cz[k] * v2[2];
        float d2 = cx[k] * v3[0] + cy[k] * v3[1] + cz[k] * v3[2];
        ssum += d2;
        mx = fmaxf(mx, fabsf(d0));
        mx = fmaxf(mx, fabsf(d1));
        mx = fmaxf(mx, fabsf(d2));
    }
    float sgn = (ssum > 0.f) ? 1.f : ((ssum < 0.f) ? -1.f : 0.f);

    // pass 2: spline conv accumulate
    float msg[FF];
#pragma unroll
    for (int f = 0; f < FF; f++) msg[f] = 0.f;

    for (int k = 0; k < KNN; k++) {
        float d0 = cx[k] * v1[0] + cy[k] * v1[1] + cz[k] * v1[2];
        float d1 = cx[k] * v2[0] + cy[k] * v2[1] + cz[k] * v2[2];
        float d2 = cx[k] * v3[0] + cy[k] * v3[1] + cz[k] * v3[2];
        d2 *= sgn;
        float u0 = d0 / mx * 0.5f + 0.5f;
        float u1 = d1 / mx * 0.5f + 0.5f;
        float u2 = d2 / mx * 0.5f + 0.5f;
        float vv0 = u0 * (KS - 1), vv1 = u1 * (KS - 1), vv2 = u2 * (KS - 1);
        float f0 = floorf(vv0), f1 = floorf(vv1), f2 = floorf(vv2);
        float fr0 = vv0 - f0, fr1 = vv1 - f1, fr2 = vv2 - f2;
        int fi0 = (int)f0, fi1 = (int)f1, fi2 = (int)f2;
#pragma unroll
        for (int s = 0; s < 8; s++) {
            int b0 = (s >> 2) & 1, b1 = (s >> 1) & 1, b2s = s & 1;
            int i0 = fi0 + b0; i0 = i0 > KS - 1 ? KS - 1 : i0;
            int i1 = fi1 + b1; i1 = i1 > KS - 1 ? KS - 1 : i1;
            int i2 = fi2 + b2s; i2 = i2 > KS - 1 ? KS - 1 : i2;
            float w = (b0 ? fr0 : 1.f - fr0) * (b1 ? fr1 : 1.f - fr1) *
                      (b2s ? fr2 : 1.f - fr2);
            int flat = (i0 * KS + i1) * KS + i2;
#pragma unroll
            for (int f = 0; f < FF; f++) msg[f] += w * sWt[f * 125 + flat];
        }
    }

#pragma unroll
    for (int f = 0; f < FF; f++)
        node[(size_t)n * FF + f] = msg[f] * (1.0f / KNN) + root[f] + bias[f];
    v3out[n * 3 + 0] = v3[0];
    v3out[n * 3 + 1] = v3[1];
    v3out[n * 3 + 2] = v3[2];
}

// ---------------------------------------------------------------------------
// Kernel 3: batch-norm statistics (sum, sumsq per feature) via atomics.
// ---------------------------------------------------------------------------
__global__ __launch_bounds__(256) void bn_stats_kernel(const float* __restrict__ node,
                                                       float* __restrict__ sums) {
    __shared__ float ls[256];
    __shared__ float ls2[256];
    float s = 0.f, s2 = 0.f;
    int total = NPTS * FF;
    for (int i = blockIdx.x * 256 + threadIdx.x; i < total; i += gridDim.x * 256) {
        float x = node[i];
        s += x;
        s2 += x * x;
    }
    ls[threadIdx.x] = s;
    ls2[threadIdx.x] = s2;
    __syncthreads();
    if (threadIdx.x < FF) {
        float a = 0.f, b = 0.f;
        for (int t = threadIdx.x; t < 256; t += FF) {
            a += ls[t];
            b += ls2[t];
        }
        atomicAdd(&sums[threadIdx.x], a);
        atomicAdd(&sums[FF + threadIdx.x], b);
    }
}

// ---------------------------------------------------------------------------
// Kernel 4: apply BN, scale normal, sigmoid, and reduce to ys (24, 32).
// flat index t = n*96 + f*3 + c regrouped as (g, p, f2): t = g*131072 + p*32 + f2
// Thread stride 256 pins bucket f2 = tid & 31.
// ---------------------------------------------------------------------------
__global__ __launch_bounds__(256) void ys_kernel(
    const float* __restrict__ node, const float* __restrict__ v3,
    const float* __restrict__ sums, const float* __restrict__ gamma,
    const float* __restrict__ beta, float* __restrict__ ys) {
    __shared__ float sa[FF], sb[FF];
    if (threadIdx.x < FF) {
        int f = threadIdx.x;
        float mu = sums[f] * (1.0f / NPTS);
        float var = sums[FF + f] * (1.0f / NPTS) - mu * mu;
        float inv = 1.0f / sqrtf(var + 1e-5f);
        sa[f] = gamma[f] * inv;
        sb[f] = beta[f] - gamma[f] * inv * mu;
    }
    __syncthreads();

    int g = blockIdx.x;
    float acc = 0.f;
    for (int i = threadIdx.x; i < GROUPLEN; i += 256) {
        int t = g * GROUPLEN + i;
        int n = t / 96;
        int r = t - n * 96;
        int f = r / 3;
        int c = r - f * 3;
        float xb = sa[f] * node[(size_t)n * FF + f] + sb[f];
        float val = xb * v3[n * 3 + c];
        acc += 1.0f / (1.0f + expf(-val));
    }
    __shared__ float red[256];
    red[threadIdx.x] = acc;
    __syncthreads();
    if (threadIdx.x < FF) {
        float s = 0.f;
        for (int t = threadIdx.x; t < 256; t += FF) s += red[t];
        ys[g * FF + threadIdx.x] = s * (1.0f / PP);
    }
}

// ---------------------------------------------------------------------------
// Kernel 5: tiny MLP head: elu(ys@W1+b1) @ W2 + b2 -> log_softmax. 1 block/row.
// ---------------------------------------------------------------------------
__global__ __launch_bounds__(256) void head_kernel(
    const float* __restrict__ ys, const float* __restrict__ W1,
    const float* __restrict__ b1, const float* __restrict__ W2,
    const float* __restrict__ b2, float* __restrict__ out) {
    int g = blockIdx.x;
    __shared__ float syr[FF];
    __shared__ float h[256];
    __shared__ float logits[NCLS];
    __shared__ float mstat[2];
    if (threadIdx.x < FF) syr[threadIdx.x] = ys[g * FF + threadIdx.x];
    __syncthreads();
    int j = threadIdx.x;
    float acc = b1[j];
#pragma unroll
    for (int f = 0; f < FF; f++) acc += syr[f] * W1[f * 256 + j];
    h[j] = acc > 0.f ? acc : expm1f(acc);
    __syncthreads();
    if (j < NCLS) {
        float l = b2[j];
        for (int q = 0; q < 256; q++) l += h[q] * W2[q * NCLS + j];
        logits[j] = l;
    }
    __syncthreads();
    if (j == 0) {
        float m = -INFINITY;
        for (int o = 0; o < NCLS; o++) m = fmaxf(m, logits[o]);
        float s = 0.f;
        for (int o = 0; o < NCLS; o++) s += expf(logits[o] - m);
        mstat[0] = m;
        mstat[1] = logf(s);
    }
    __syncthreads();
    if (j < NCLS) out[g * NCLS + j] = logits[j] - mstat[0] - mstat[1];
}

// ---------------------------------------------------------------------------
extern "C" void kernel_launch(void* const* d_in, const int* in_sizes, int n_in,
                              void* d_out, int out_size, void* d_ws, size_t ws_size,
                              hipStream_t stream) {
    const float* pos   = (const float*)d_in[0];
    const float* Wsp   = (const float*)d_in[1];
    const float* root  = (const float*)d_in[2];
    const float* bias  = (const float*)d_in[3];
    const float* gamma = (const float*)d_in[4];
    const float* beta  = (const float*)d_in[5];
    const float* W1    = (const float*)d_in[6];
    const float* b1    = (const float*)d_in[7];
    const float* W2    = (const float*)d_in[8];
    const float* b2    = (const float*)d_in[9];
    float* out = (float*)d_out;

    char* ws = (char*)d_ws;
    int* nbr    = (int*)(ws);                      // 32768*20*4   = 2621440 B
    float* node = (float*)(ws + 2621440);          // 32768*32*4   = 4194304 B
    float* v3   = (float*)(ws + 6815744);          // 32768*3*4    = 393216 B
    float* sums = (float*)(ws + 7208960);          // 64*4         = 256 B
    float* ys   = (float*)(ws + 7209216);          // 24*32*4      = 3072 B

    hipMemsetAsync(sums, 0, 64 * sizeof(float), stream);

    knn_kernel<<<128, 256, 0, stream>>>(pos, nbr);
    point_kernel<<<128, 256, 0, stream>>>(pos, nbr, Wsp, root, bias, node, v3);
    bn_stats_kernel<<<64, 256, 0, stream>>>(node, sums);
    ys_kernel<<<NGROUP, 256, 0, stream>>>(node, v3, sums, gamma, beta, ys);
    head_kernel<<<NGROUP, 256, 0, stream>>>(ys, W1, b1, W2, b2, out);
}

// Round 3
// 838.192 us; speedup vs baseline: 3.1818x; 3.1818x over previous
//
#include <hip/hip_runtime.h>
#include <hip/hip_bf16.h>
#include <math.h>

// Problem constants
#define BGR 8        // graphs
#define PP 4096      // points per graph
#define NPTS 32768   // B*P
#define KNN 20
#define LCOV 10
#define FF 32
#define KS 5
#define NCLS 40
#define NGROUP 24    // 3*B, rows of ys
#define GROUPLEN 131072  // P*F flat elements per group

// KNN tiling
#define SPLIT 2
#define CHUNK (PP / SPLIT)        // 2048 candidates per thread
#define PTSBLK 128                // points per block (256 threads = 128 pts x 2 halves)
#define CAP 4                     // per-lane candidate buffer

// ---------------------------------------------------------------------------
// Kernel 1: brute-force KNN per graph.
// 256 blocks: each handles 128 points of one graph; thread t = (half, pt).
// Top-20 kept in REGISTERS via a fully-unrolled compare-select insertion
// network; candidates are buffered per-lane (4 slots, select-chain append)
// and flushed wave-uniformly when any lane's buffer fills (ballot gate).
// Two half-range sorted lists per point are merged via LDS at the end.
// LDS layout: one 48 KB arena. Staging phase: sx|sy|sz (3*4096 floats).
// Merge phase REUSES the arena with explicit non-overlapping offsets:
//   md = smem[0 .. 5119]            (2*128*20 floats)
//   mi = (int*)&smem[5120 .. 10239] (2*128*20 ints)   -- 10240 <= 12288. OK.
// (Round-2 bug: md/mi were aliased via sx/sy and collided -> OOB reads.)
// ---------------------------------------------------------------------------
__global__ __launch_bounds__(256) void knn_kernel(const float* __restrict__ pos,
                                                  int* __restrict__ nbr) {
    __shared__ float smem[3 * PP];   // 48 KB arena
    float* sx = smem;
    float* sy = smem + PP;
    float* sz = smem + 2 * PP;

    int b = blockIdx.x >> 5;          // 32 blocks per graph
    int blkInGraph = blockIdx.x & 31;
    const float* gp = pos + (size_t)b * PP * 3;
    for (int i = threadIdx.x; i < PP; i += 256) {
        sx[i] = gp[i * 3 + 0];
        sy[i] = gp[i * 3 + 1];
        sz[i] = gp[i * 3 + 2];
    }
    __syncthreads();

    int half = threadIdx.x >> 7;          // 0 or 1
    int pt = threadIdx.x & (PTSBLK - 1);  // 0..127
    int li = blkInGraph * PTSBLK + pt;    // local point index in graph
    float px = sx[li], py = sy[li], pz = sz[li];

    float bd[KNN];
    int bi[KNN];
#pragma unroll
    for (int k = 0; k < KNN; k++) { bd[k] = INFINITY; bi[k] = 0; }
    float worst = INFINITY;

    float bufd[CAP];
    int bufi[CAP];
    int cnt = 0;
#pragma unroll
    for (int s = 0; s < CAP; s++) { bufd[s] = INFINITY; bufi[s] = 0; }

    auto flush = [&]() {
#pragma unroll
        for (int s = 0; s < CAP; s++) {
            float d = bufd[s];
            int idx = bufi[s];
#pragma unroll
            for (int k = 0; k < KNN; k++) {
                bool c = d < bd[k];         // strict: ties keep earlier index
                float tb = bd[k];
                int ti = bi[k];
                bd[k] = c ? d : tb;
                bi[k] = c ? idx : ti;
                d = c ? tb : d;
                idx = c ? ti : idx;
            }
            bufd[s] = INFINITY;
        }
        cnt = 0;
        worst = bd[KNN - 1];
    };

    int jbeg = half * CHUNK;
    int jend = jbeg + CHUNK;
    for (int j = jbeg; j < jend; ++j) {
        float dx = px - sx[j];
        float dy = py - sy[j];
        float dz = pz - sz[j];
        float d = dx * dx;
        d = fmaf(dy, dy, d);
        d = fmaf(dz, dz, d);
        bool pass = (d < worst) && (j != li);
        if (pass) {
#pragma unroll
            for (int s = 0; s < CAP; s++) {
                bool sel = (cnt == s);
                bufd[s] = sel ? d : bufd[s];
                bufi[s] = sel ? j : bufi[s];
            }
            cnt++;
        }
        if (__any(cnt >= CAP)) flush();
    }
    flush();

    // ---- merge the two half-range sorted lists per point via LDS ----
    __syncthreads();   // everyone done reading sx/sy/sz; arena is reusable
    float* md = smem;                          // [2][128][20] distances
    int* mi = (int*)(smem + 2 * PTSBLK * KNN); // [2][128][20] indices
#pragma unroll
    for (int k = 0; k < KNN; k++) {
        md[(half * PTSBLK + pt) * KNN + k] = bd[k];
        mi[(half * PTSBLK + pt) * KNN + k] = bi[k];
    }
    __syncthreads();
    if (threadIdx.x < PTSBLK) {
        int p = threadIdx.x;
        int ia = 0, ib = 0;
        int gi = b * PP + blkInGraph * PTSBLK + p;
        const float* da = &md[p * KNN];
        const float* db = &md[(PTSBLK + p) * KNN];
        const int* ja = &mi[p * KNN];
        const int* jb = &mi[(PTSBLK + p) * KNN];
#pragma unroll
        for (int k = 0; k < KNN; k++) {
            float va = da[ia];
            float vb = db[ib];
            bool ta = va <= vb;   // tie -> chunk A (lower index)
            int chosen = ta ? ja[ia] : jb[ib];
            nbr[gi * KNN + k] = b * PP + chosen;
            ia += ta ? 1 : 0;
            ib += ta ? 0 : 1;
        }
    }
}

// ---------------------------------------------------------------------------
// 3x3 helpers + power iteration (replicates reference arithmetic)
// ---------------------------------------------------------------------------
__device__ inline void mat3vec(const float M[9], const float v[3], float w[3]) {
    w[0] = M[0] * v[0] + M[1] * v[1] + M[2] * v[2];
    w[1] = M[3] * v[0] + M[4] * v[1] + M[5] * v[2];
    w[2] = M[6] * v[0] + M[7] * v[1] + M[8] * v[2];
}

__device__ inline float pi3(const float M[9], float v[3]) {
    v[0] = v[1] = v[2] = 0.57735026918962576f;  // 3^-0.5 as f32
#pragma unroll
    for (int it = 0; it < 5; ++it) {
        float w[3];
        mat3vec(M, v, w);
        float nrm = sqrtf(w[0] * w[0] + w[1] * w[1] + w[2] * w[2]) + 1e-12f;
        v[0] = w[0] / nrm;
        v[1] = w[1] / nrm;
        v[2] = w[2] / nrm;
    }
    float w[3];
    mat3vec(M, v, w);
    return v[0] * w[0] + v[1] * w[1] + v[2] * w[2];
}

// ---------------------------------------------------------------------------
// Kernel 2: per-point cov -> eig -> dirc -> spline conv -> node features.
// Wsp staged in LDS transposed [f][flat] (stride 125) to spread LDS banks.
// ---------------------------------------------------------------------------
__global__ __launch_bounds__(256) void point_kernel(
    const float* __restrict__ pos, const int* __restrict__ nbr,
    const float* __restrict__ Wsp, const float* __restrict__ root,
    const float* __restrict__ bias, float* __restrict__ node,
    float* __restrict__ v3out) {
    __shared__ float sWt[FF * 125];  // [f][flat]
    for (int i = threadIdx.x; i < FF * 125; i += 256) {
        int f = i / 125;
        int j = i - f * 125;
        sWt[i] = Wsp[j * FF + f];
    }
    __syncthreads();

    int n = blockIdx.x * 256 + threadIdx.x;
    float px = pos[n * 3 + 0], py = pos[n * 3 + 1], pz = pos[n * 3 + 2];

    float cx[KNN], cy[KNN], cz[KNN];
#pragma unroll
    for (int k = 0; k < KNN; k++) {
        int id = nbr[n * KNN + k];
        cx[k] = pos[id * 3 + 0] - px;
        cy[k] = pos[id * 3 + 1] - py;
        cz[k] = pos[id * 3 + 2] - pz;
    }

    // covariance over the L nearest
    float M[9] = {0.f, 0.f, 0.f, 0.f, 0.f, 0.f, 0.f, 0.f, 0.f};
#pragma unroll
    for (int m = 0; m < LCOV; m++) {
        M[0] += cx[m] * cx[m];
        M[1] += cx[m] * cy[m];
        M[2] += cx[m] * cz[m];
        M[4] += cy[m] * cy[m];
        M[5] += cy[m] * cz[m];
        M[8] += cz[m] * cz[m];
    }
    M[3] = M[1];
    M[6] = M[2];
    M[7] = M[5];

    float v1[3], v2[3], v3[3];
    float l1 = pi3(M, v1);
    float M2[9];
#pragma unroll
    for (int c = 0; c < 3; c++)
#pragma unroll
        for (int d = 0; d < 3; d++) M2[c * 3 + d] = M[c * 3 + d] - l1 * v1[c] * v1[d];
    pi3(M2, v2);
    // v3 = normalize(cross(v1, v2))
    v3[0] = v1[1] * v2[2] - v1[2] * v2[1];
    v3[1] = v1[2] * v2[0] - v1[0] * v2[2];
    v3[2] = v1[0] * v2[1] - v1[1] * v2[0];
    {
        float nrm = sqrtf(v3[0] * v3[0] + v3[1] * v3[1] + v3[2] * v3[2]) + 1e-12f;
        v3[0] /= nrm;
        v3[1] /= nrm;
        v3[2] /= nrm;
    }

    // pass 1 over neighbors: sign accumulator + max_abs
    float ssum = 0.f, mx = 0.f;
#pragma unroll
    for (int k = 0; k < KNN; k++) {
        float d0 = cx[k] * v1[0] + cy[k] * v1[1] + cz[k] * v1[2];
        float d1 = cx[k] * v2[0] + cy[k] * v2[1] + cz[k] * v2[2];
        float d2 = cx[k] * v3[0] + cy[k] * v3[1] + cz[k] * v3[2];
        ssum += d2;
        mx = fmaxf(mx, fabsf(d0));
        mx = fmaxf(mx, fabsf(d1));
        mx = fmaxf(mx, fabsf(d2));
    }
    float sgn = (ssum > 0.f) ? 1.f : ((ssum < 0.f) ? -1.f : 0.f);

    // pass 2: spline conv accumulate
    float msg[FF];
#pragma unroll
    for (int f = 0; f < FF; f++) msg[f] = 0.f;

#pragma unroll
    for (int k = 0; k < KNN; k++) {
        float d0 = cx[k] * v1[0] + cy[k] * v1[1] + cz[k] * v1[2];
        float d1 = cx[k] * v2[0] + cy[k] * v2[1] + cz[k] * v2[2];
        float d2 = cx[k] * v3[0] + cy[k] * v3[1] + cz[k] * v3[2];
        d2 *= sgn;
        float u0 = d0 / mx * 0.5f + 0.5f;
        float u1 = d1 / mx * 0.5f + 0.5f;
        float u2 = d2 / mx * 0.5f + 0.5f;
        float vv0 = u0 * (KS - 1), vv1 = u1 * (KS - 1), vv2 = u2 * (KS - 1);
        float f0 = floorf(vv0), f1 = floorf(vv1), f2 = floorf(vv2);
        float fr0 = vv0 - f0, fr1 = vv1 - f1, fr2 = vv2 - f2;
        int fi0 = (int)f0, fi1 = (int)f1, fi2 = (int)f2;
#pragma unroll
        for (int s = 0; s < 8; s++) {
            int b0 = (s >> 2) & 1, b1 = (s >> 1) & 1, b2s = s & 1;
            int i0 = fi0 + b0; i0 = i0 > KS - 1 ? KS - 1 : i0;
            int i1 = fi1 + b1; i1 = i1 > KS - 1 ? KS - 1 : i1;
            int i2 = fi2 + b2s; i2 = i2 > KS - 1 ? KS - 1 : i2;
            float w = (b0 ? fr0 : 1.f - fr0) * (b1 ? fr1 : 1.f - fr1) *
                      (b2s ? fr2 : 1.f - fr2);
            int flat = (i0 * KS + i1) * KS + i2;
#pragma unroll
            for (int f = 0; f < FF; f++) msg[f] += w * sWt[f * 125 + flat];
        }
    }

#pragma unroll
    for (int f = 0; f < FF; f++)
        node[(size_t)n * FF + f] = msg[f] * (1.0f / KNN) + root[f] + bias[f];
    v3out[n * 3 + 0] = v3[0];
    v3out[n * 3 + 1] = v3[1];
    v3out[n * 3 + 2] = v3[2];
}

// ---------------------------------------------------------------------------
// Kernel 3: batch-norm statistics (sum, sumsq per feature) via atomics.
// ---------------------------------------------------------------------------
__global__ __launch_bounds__(256) void bn_stats_kernel(const float* __restrict__ node,
                                                       float* __restrict__ sums) {
    __shared__ float ls[256];
    __shared__ float ls2[256];
    float s = 0.f, s2 = 0.f;
    int total = NPTS * FF;
    for (int i = blockIdx.x * 256 + threadIdx.x; i < total; i += gridDim.x * 256) {
        float x = node[i];
        s += x;
        s2 += x * x;
    }
    ls[threadIdx.x] = s;
    ls2[threadIdx.x] = s2;
    __syncthreads();
    if (threadIdx.x < FF) {
        float a = 0.f, b = 0.f;
        for (int t = threadIdx.x; t < 256; t += FF) {
            a += ls[t];
            b += ls2[t];
        }
        atomicAdd(&sums[threadIdx.x], a);
        atomicAdd(&sums[FF + threadIdx.x], b);
    }
}

// ---------------------------------------------------------------------------
// Kernel 4: apply BN, scale normal, sigmoid, and reduce to ys (24, 32).
// flat index t = n*96 + f*3 + c regrouped as (g, p, f2): t = g*131072 + p*32 + f2
// Thread stride 256 pins bucket f2 = tid & 31.
// ---------------------------------------------------------------------------
__global__ __launch_bounds__(256) void ys_kernel(
    const float* __restrict__ node, const float* __restrict__ v3,
    const float* __restrict__ sums, const float* __restrict__ gamma,
    const float* __restrict__ beta, float* __restrict__ ys) {
    __shared__ float sa[FF], sb[FF];
    if (threadIdx.x < FF) {
        int f = threadIdx.x;
        float mu = sums[f] * (1.0f / NPTS);
        float var = sums[FF + f] * (1.0f / NPTS) - mu * mu;
        float inv = 1.0f / sqrtf(var + 1e-5f);
        sa[f] = gamma[f] * inv;
        sb[f] = beta[f] - gamma[f] * inv * mu;
    }
    __syncthreads();

    int g = blockIdx.x;
    float acc = 0.f;
    for (int i = threadIdx.x; i < GROUPLEN; i += 256) {
        int t = g * GROUPLEN + i;
        int n = t / 96;
        int r = t - n * 96;
        int f = r / 3;
        int c = r - f * 3;
        float xb = sa[f] * node[(size_t)n * FF + f] + sb[f];
        float val = xb * v3[n * 3 + c];
        acc += 1.0f / (1.0f + expf(-val));
    }
    __shared__ float red[256];
    red[threadIdx.x] = acc;
    __syncthreads();
    if (threadIdx.x < FF) {
        float s = 0.f;
        for (int t = threadIdx.x; t < 256; t += FF) s += red[t];
        ys[g * FF + threadIdx.x] = s * (1.0f / PP);
    }
}

// ---------------------------------------------------------------------------
// Kernel 5: tiny MLP head: elu(ys@W1+b1) @ W2 + b2 -> log_softmax. 1 block/row.
// ---------------------------------------------------------------------------
__global__ __launch_bounds__(256) void head_kernel(
    const float* __restrict__ ys, const float* __restrict__ W1,
    const float* __restrict__ b1, const float* __restrict__ W2,
    const float* __restrict__ b2, float* __restrict__ out) {
    int g = blockIdx.x;
    __shared__ float syr[FF];
    __shared__ float h[256];
    __shared__ float logits[NCLS];
    __shared__ float mstat[2];
    if (threadIdx.x < FF) syr[threadIdx.x] = ys[g * FF + threadIdx.x];
    __syncthreads();
    int j = threadIdx.x;
    float acc = b1[j];
#pragma unroll
    for (int f = 0; f < FF; f++) acc += syr[f] * W1[f * 256 + j];
    h[j] = acc > 0.f ? acc : expm1f(acc);
    __syncthreads();
    if (j < NCLS) {
        float l = b2[j];
        for (int q = 0; q < 256; q++) l += h[q] * W2[q * NCLS + j];
        logits[j] = l;
    }
    __syncthreads();
    if (j == 0) {
        float m = -INFINITY;
        for (int o = 0; o < NCLS; o++) m = fmaxf(m, logits[o]);
        float s = 0.f;
        for (int o = 0; o < NCLS; o++) s += expf(logits[o] - m);
        mstat[0] = m;
        mstat[1] = logf(s);
    }
    __syncthreads();
    if (j < NCLS) out[g * NCLS + j] = logits[j] - mstat[0] - mstat[1];
}

// ---------------------------------------------------------------------------
extern "C" void kernel_launch(void* const* d_in, const int* in_sizes, int n_in,
                              void* d_out, int out_size, void* d_ws, size_t ws_size,
                              hipStream_t stream) {
    const float* pos   = (const float*)d_in[0];
    const float* Wsp   = (const float*)d_in[1];
    const float* root  = (const float*)d_in[2];
    const float* bias  = (const float*)d_in[3];
    const float* gamma = (const float*)d_in[4];
    const float* beta  = (const float*)d_in[5];
    const float* W1    = (const float*)d_in[6];
    const float* b1    = (const float*)d_in[7];
    const float* W2    = (const float*)d_in[8];
    const float* b2    = (const float*)d_in[9];
    float* out = (float*)d_out;

    char* ws = (char*)d_ws;
    int* nbr    = (int*)(ws);                      // 32768*20*4   = 2621440 B
    float* node = (float*)(ws + 2621440);          // 32768*32*4   = 4194304 B
    float* v3   = (float*)(ws + 6815744);          // 32768*3*4    = 393216 B
    float* sums = (float*)(ws + 7208960);          // 64*4         = 256 B
    float* ys   = (float*)(ws + 7209216);          // 24*32*4      = 3072 B

    hipMemsetAsync(sums, 0, 64 * sizeof(float), stream);

    knn_kernel<<<256, 256, 0, stream>>>(pos, nbr);
    point_kernel<<<128, 256, 0, stream>>>(pos, nbr, Wsp, root, bias, node, v3);
    bn_stats_kernel<<<64, 256, 0, stream>>>(node, sums);
    ys_kernel<<<NGROUP, 256, 0, stream>>>(node, v3, sums, gamma, beta, ys);
    head_kernel<<<NGROUP, 256, 0, stream>>>(ys, W1, b1, W2, b2, out);
}

// Round 4
// 473.018 us; speedup vs baseline: 5.6381x; 1.7720x over previous
//
#include <hip/hip_runtime.h>
#include <hip/hip_bf16.h>
#include <math.h>

// Problem constants
#define BGR 8        // graphs
#define PP 4096      // points per graph
#define NPTS 32768   // B*P
#define KNN 20
#define LCOV 10
#define FF 32
#define KS 5
#define NCLS 40
#define NGROUP 24    // 3*B, rows of ys
#define GROUPLEN 131072  // P*F flat elements per group

// KNN tiling: 512 blocks = 64 blocks/graph; 256 thr = 64 pts x 4 range-quarters
#define SPLIT 4
#define CHUNK (PP / SPLIT)        // 1024 candidates per thread
#define PTSBLK 64                 // points per block
#define CAP 4                     // per-lane candidate buffer

// ---------------------------------------------------------------------------
// Kernel 1: brute-force KNN per graph.
// 512 blocks: each handles 64 points of one graph; thread t = (quarter, pt).
// Top-20 kept in REGISTERS via a fully-unrolled compare-select insertion
// network; candidates buffered per-lane (4 slots) and flushed wave-uniformly
// (ballot gate). Four quarter-range sorted lists merged per point via LDS.
// Occupancy note: 48 KB LDS -> 3 blocks/CU possible; grid 512 = 2 blocks/CU
// co-resident (8 waves/CU), which is what Round-3's 1-wave/SIMD config lacked.
// ---------------------------------------------------------------------------
__global__ __launch_bounds__(256) void knn_kernel(const float* __restrict__ pos,
                                                  int* __restrict__ nbr) {
    __shared__ float smem[3 * PP];   // 48 KB arena
    float* sx = smem;
    float* sy = smem + PP;
    float* sz = smem + 2 * PP;

    int b = blockIdx.x >> 6;          // 64 blocks per graph
    int blkInGraph = blockIdx.x & 63;
    const float* gp = pos + (size_t)b * PP * 3;
    for (int i = threadIdx.x; i < PP; i += 256) {
        sx[i] = gp[i * 3 + 0];
        sy[i] = gp[i * 3 + 1];
        sz[i] = gp[i * 3 + 2];
    }
    __syncthreads();

    int quarter = threadIdx.x >> 6;       // 0..3 (one wave per quarter)
    int pt = threadIdx.x & (PTSBLK - 1);  // 0..63
    int li = blkInGraph * PTSBLK + pt;    // local point index in graph
    float px = sx[li], py = sy[li], pz = sz[li];

    float bd[KNN];
    int bi[KNN];
#pragma unroll
    for (int k = 0; k < KNN; k++) { bd[k] = INFINITY; bi[k] = 0; }
    float worst = INFINITY;

    float bufd[CAP];
    int bufi[CAP];
    int cnt = 0;
#pragma unroll
    for (int s = 0; s < CAP; s++) { bufd[s] = INFINITY; bufi[s] = 0; }

    auto flush = [&]() {
#pragma unroll
        for (int s = 0; s < CAP; s++) {
            float d = bufd[s];
            int idx = bufi[s];
#pragma unroll
            for (int k = 0; k < KNN; k++) {
                bool c = d < bd[k];         // strict: ties keep earlier index
                float tb = bd[k];
                int ti = bi[k];
                bd[k] = c ? d : tb;
                bi[k] = c ? idx : ti;
                d = c ? tb : d;
                idx = c ? ti : idx;
            }
            bufd[s] = INFINITY;
        }
        cnt = 0;
        worst = bd[KNN - 1];
    };

    int jbeg = quarter * CHUNK;
    int jend = jbeg + CHUNK;
    for (int j = jbeg; j < jend; ++j) {
        float dx = px - sx[j];
        float dy = py - sy[j];
        float dz = pz - sz[j];
        float d = dx * dx;
        d = fmaf(dy, dy, d);
        d = fmaf(dz, dz, d);
        bool pass = (d < worst) && (j != li);
        if (pass) {
#pragma unroll
            for (int s = 0; s < CAP; s++) {
                bool sel = (cnt == s);
                bufd[s] = sel ? d : bufd[s];
                bufi[s] = sel ? j : bufi[s];
            }
            cnt++;
        }
        if (__any(cnt >= CAP)) flush();
    }
    flush();

    // ---- merge the four quarter-range sorted lists per point via LDS ----
    // Arena reuse (post-barrier): md = smem[0..5119] floats, mi = next 5120 ints
    // (4*64*20 = 5120 each; 10240 words <= 12288 available). No aliasing.
    __syncthreads();
    float* md = smem;                            // [4][64][20] distances
    int* mi = (int*)(smem + SPLIT * PTSBLK * KNN); // [4][64][20] indices
#pragma unroll
    for (int k = 0; k < KNN; k++) {
        md[(quarter * PTSBLK + pt) * KNN + k] = bd[k];
        mi[(quarter * PTSBLK + pt) * KNN + k] = bi[k];
    }
    __syncthreads();
    if (threadIdx.x < PTSBLK) {
        int p = threadIdx.x;
        const float* da = &md[(0 * PTSBLK + p) * KNN];
        const float* db = &md[(1 * PTSBLK + p) * KNN];
        const float* dc = &md[(2 * PTSBLK + p) * KNN];
        const float* dd = &md[(3 * PTSBLK + p) * KNN];
        const int* ja = &mi[(0 * PTSBLK + p) * KNN];
        const int* jb = &mi[(1 * PTSBLK + p) * KNN];
        const int* jc = &mi[(2 * PTSBLK + p) * KNN];
        const int* jd = &mi[(3 * PTSBLK + p) * KNN];
        int ia = 0, ib = 0, ic = 0, id = 0;
        int gi = b * PP + blkInGraph * PTSBLK + p;
#pragma unroll
        for (int k = 0; k < KNN; k++) {
            // sentinel reads keep exhausted lists out of the running
            float va = (ia < KNN) ? da[ia] : INFINITY;
            float vb = (ib < KNN) ? db[ib] : INFINITY;
            float vc = (ic < KNN) ? dc[ic] : INFINITY;
            float vd = (id < KNN) ? dd[id] : INFINITY;
            // strict < keeps lowest chunk (= lowest index) on ties
            float m = va; int src = 0;
            if (vb < m) { m = vb; src = 1; }
            if (vc < m) { m = vc; src = 2; }
            if (vd < m) { m = vd; src = 3; }
            int chosen = (src == 0) ? ja[ia] : (src == 1) ? jb[ib]
                       : (src == 2) ? jc[ic] : jd[id];
            nbr[gi * KNN + k] = b * PP + chosen;
            ia += (src == 0);
            ib += (src == 1);
            ic += (src == 2);
            id += (src == 3);
        }
    }
}

// ---------------------------------------------------------------------------
// 3x3 helpers + power iteration (replicates reference arithmetic)
// ---------------------------------------------------------------------------
__device__ inline void mat3vec(const float M[9], const float v[3], float w[3]) {
    w[0] = M[0] * v[0] + M[1] * v[1] + M[2] * v[2];
    w[1] = M[3] * v[0] + M[4] * v[1] + M[5] * v[2];
    w[2] = M[6] * v[0] + M[7] * v[1] + M[8] * v[2];
}

__device__ inline float pi3(const float M[9], float v[3]) {
    v[0] = v[1] = v[2] = 0.57735026918962576f;  // 3^-0.5 as f32
#pragma unroll
    for (int it = 0; it < 5; ++it) {
        float w[3];
        mat3vec(M, v, w);
        float nrm = sqrtf(w[0] * w[0] + w[1] * w[1] + w[2] * w[2]) + 1e-12f;
        v[0] = w[0] / nrm;
        v[1] = w[1] / nrm;
        v[2] = w[2] / nrm;
    }
    float w[3];
    mat3vec(M, v, w);
    return v[0] * w[0] + v[1] * w[1] + v[2] * w[2];
}

// ---------------------------------------------------------------------------
// Kernel 2: per-point cov -> eig -> dirc -> spline conv -> node features.
// 256 blocks x 128 threads (fills all 256 CUs; R3 grid used only half).
// Wsp staged in LDS transposed [f][flat] (stride 125) to spread LDS banks.
// ---------------------------------------------------------------------------
__global__ __launch_bounds__(128) void point_kernel(
    const float* __restrict__ pos, const int* __restrict__ nbr,
    const float* __restrict__ Wsp, const float* __restrict__ root,
    const float* __restrict__ bias, float* __restrict__ node,
    float* __restrict__ v3out) {
    __shared__ float sWt[FF * 125];  // [f][flat]
    for (int i = threadIdx.x; i < FF * 125; i += 128) {
        int f = i / 125;
        int j = i - f * 125;
        sWt[i] = Wsp[j * FF + f];
    }
    __syncthreads();

    int n = blockIdx.x * 128 + threadIdx.x;
    float px = pos[n * 3 + 0], py = pos[n * 3 + 1], pz = pos[n * 3 + 2];

    float cx[KNN], cy[KNN], cz[KNN];
#pragma unroll
    for (int k = 0; k < KNN; k++) {
        int id = nbr[n * KNN + k];
        cx[k] = pos[id * 3 + 0] - px;
        cy[k] = pos[id * 3 + 1] - py;
        cz[k] = pos[id * 3 + 2] - pz;
    }

    // covariance over the L nearest
    float M[9] = {0.f, 0.f, 0.f, 0.f, 0.f, 0.f, 0.f, 0.f, 0.f};
#pragma unroll
    for (int m = 0; m < LCOV; m++) {
        M[0] += cx[m] * cx[m];
        M[1] += cx[m] * cy[m];
        M[2] += cx[m] * cz[m];
        M[4] += cy[m] * cy[m];
        M[5] += cy[m] * cz[m];
        M[8] += cz[m] * cz[m];
    }
    M[3] = M[1];
    M[6] = M[2];
    M[7] = M[5];

    float v1[3], v2[3], v3[3];
    float l1 = pi3(M, v1);
    float M2[9];
#pragma unroll
    for (int c = 0; c < 3; c++)
#pragma unroll
        for (int d = 0; d < 3; d++) M2[c * 3 + d] = M[c * 3 + d] - l1 * v1[c] * v1[d];
    pi3(M2, v2);
    // v3 = normalize(cross(v1, v2))
    v3[0] = v1[1] * v2[2] - v1[2] * v2[1];
    v3[1] = v1[2] * v2[0] - v1[0] * v2[2];
    v3[2] = v1[0] * v2[1] - v1[1] * v2[0];
    {
        float nrm = sqrtf(v3[0] * v3[0] + v3[1] * v3[1] + v3[2] * v3[2]) + 1e-12f;
        v3[0] /= nrm;
        v3[1] /= nrm;
        v3[2] /= nrm;
    }

    // pass 1 over neighbors: sign accumulator + max_abs
    float ssum = 0.f, mx = 0.f;
#pragma unroll
    for (int k = 0; k < KNN; k++) {
        float d0 = cx[k] * v1[0] + cy[k] * v1[1] + cz[k] * v1[2];
        float d1 = cx[k] * v2[0] + cy[k] * v2[1] + cz[k] * v2[2];
        float d2 = cx[k] * v3[0] + cy[k] * v3[1] + cz[k] * v3[2];
        ssum += d2;
        mx = fmaxf(mx, fabsf(d0));
        mx = fmaxf(mx, fabsf(d1));
        mx = fmaxf(mx, fabsf(d2));
    }
    float sgn = (ssum > 0.f) ? 1.f : ((ssum < 0.f) ? -1.f : 0.f);

    // pass 2: spline conv accumulate
    float msg[FF];
#pragma unroll
    for (int f = 0; f < FF; f++) msg[f] = 0.f;

#pragma unroll
    for (int k = 0; k < KNN; k++) {
        float d0 = cx[k] * v1[0] + cy[k] * v1[1] + cz[k] * v1[2];
        float d1 = cx[k] * v2[0] + cy[k] * v2[1] + cz[k] * v2[2];
        float d2 = cx[k] * v3[0] + cy[k] * v3[1] + cz[k] * v3[2];
        d2 *= sgn;
        float u0 = d0 / mx * 0.5f + 0.5f;
        float u1 = d1 / mx * 0.5f + 0.5f;
        float u2 = d2 / mx * 0.5f + 0.5f;
        float vv0 = u0 * (KS - 1), vv1 = u1 * (KS - 1), vv2 = u2 * (KS - 1);
        float f0 = floorf(vv0), f1 = floorf(vv1), f2 = floorf(vv2);
        float fr0 = vv0 - f0, fr1 = vv1 - f1, fr2 = vv2 - f2;
        int fi0 = (int)f0, fi1 = (int)f1, fi2 = (int)f2;
#pragma unroll
        for (int s = 0; s < 8; s++) {
            int b0 = (s >> 2) & 1, b1 = (s >> 1) & 1, b2s = s & 1;
            int i0 = fi0 + b0; i0 = i0 > KS - 1 ? KS - 1 : i0;
            int i1 = fi1 + b1; i1 = i1 > KS - 1 ? KS - 1 : i1;
            int i2 = fi2 + b2s; i2 = i2 > KS - 1 ? KS - 1 : i2;
            float w = (b0 ? fr0 : 1.f - fr0) * (b1 ? fr1 : 1.f - fr1) *
                      (b2s ? fr2 : 1.f - fr2);
            int flat = (i0 * KS + i1) * KS + i2;
#pragma unroll
            for (int f = 0; f < FF; f++) msg[f] += w * sWt[f * 125 + flat];
        }
    }

#pragma unroll
    for (int f = 0; f < FF; f++)
        node[(size_t)n * FF + f] = msg[f] * (1.0f / KNN) + root[f] + bias[f];
    v3out[n * 3 + 0] = v3[0];
    v3out[n * 3 + 1] = v3[1];
    v3out[n * 3 + 2] = v3[2];
}

// ---------------------------------------------------------------------------
// Kernel 3: batch-norm statistics (sum, sumsq per feature) via atomics.
// ---------------------------------------------------------------------------
__global__ __launch_bounds__(256) void bn_stats_kernel(const float* __restrict__ node,
                                                       float* __restrict__ sums) {
    __shared__ float ls[256];
    __shared__ float ls2[256];
    float s = 0.f, s2 = 0.f;
    int total = NPTS * FF;
    for (int i = blockIdx.x * 256 + threadIdx.x; i < total; i += gridDim.x * 256) {
        float x = node[i];
        s += x;
        s2 += x * x;
    }
    ls[threadIdx.x] = s;
    ls2[threadIdx.x] = s2;
    __syncthreads();
    if (threadIdx.x < FF) {
        float a = 0.f, b = 0.f;
        for (int t = threadIdx.x; t < 256; t += FF) {
            a += ls[t];
            b += ls2[t];
        }
        atomicAdd(&sums[threadIdx.x], a);
        atomicAdd(&sums[FF + threadIdx.x], b);
    }
}

// ---------------------------------------------------------------------------
// Kernel 4: apply BN, scale normal, sigmoid, reduce to ys (24, 32).
// Grid 24 groups x 8 p-range splits = 192 blocks; partials via atomicAdd
// into zeroed ys. Bucket invariant: i-range offsets are multiples of 32, so
// thread tid always accumulates feature f2 = tid & 31.
// ---------------------------------------------------------------------------
#define YSPLIT 8
#define YCHUNK (GROUPLEN / YSPLIT)   // 16384
__global__ __launch_bounds__(256) void ys_kernel(
    const float* __restrict__ node, const float* __restrict__ v3,
    const float* __restrict__ sums, const float* __restrict__ gamma,
    const float* __restrict__ beta, float* __restrict__ ys) {
    __shared__ float sa[FF], sb[FF];
    if (threadIdx.x < FF) {
        int f = threadIdx.x;
        float mu = sums[f] * (1.0f / NPTS);
        float var = sums[FF + f] * (1.0f / NPTS) - mu * mu;
        float inv = 1.0f / sqrtf(var + 1e-5f);
        sa[f] = gamma[f] * inv;
        sb[f] = beta[f] - gamma[f] * inv * mu;
    }
    __syncthreads();

    int g = blockIdx.x >> 3;
    int sub = blockIdx.x & 7;
    float acc = 0.f;
    int ibeg = sub * YCHUNK + threadIdx.x;
    int iend = (sub + 1) * YCHUNK;
    for (int i = ibeg; i < iend; i += 256) {
        int t = g * GROUPLEN + i;
        int n = t / 96;
        int r = t - n * 96;
        int f = r / 3;
        int c = r - f * 3;
        float xb = sa[f] * node[(size_t)n * FF + f] + sb[f];
        float val = xb * v3[n * 3 + c];
        acc += 1.0f / (1.0f + expf(-val));
    }
    __shared__ float red[256];
    red[threadIdx.x] = acc;
    __syncthreads();
    if (threadIdx.x < FF) {
        float s = 0.f;
        for (int t = threadIdx.x; t < 256; t += FF) s += red[t];
        atomicAdd(&ys[g * FF + threadIdx.x], s * (1.0f / PP));
    }
}

// ---------------------------------------------------------------------------
// Kernel 5: tiny MLP head: elu(ys@W1+b1) @ W2 + b2 -> log_softmax. 1 block/row.
// ---------------------------------------------------------------------------
__global__ __launch_bounds__(256) void head_kernel(
    const float* __restrict__ ys, const float* __restrict__ W1,
    const float* __restrict__ b1, const float* __restrict__ W2,
    const float* __restrict__ b2, float* __restrict__ out) {
    int g = blockIdx.x;
    __shared__ float syr[FF];
    __shared__ float h[256];
    __shared__ float logits[NCLS];
    __shared__ float mstat[2];
    if (threadIdx.x < FF) syr[threadIdx.x] = ys[g * FF + threadIdx.x];
    __syncthreads();
    int j = threadIdx.x;
    float acc = b1[j];
#pragma unroll
    for (int f = 0; f < FF; f++) acc += syr[f] * W1[f * 256 + j];
    h[j] = acc > 0.f ? acc : expm1f(acc);
    __syncthreads();
    if (j < NCLS) {
        float l = b2[j];
        for (int q = 0; q < 256; q++) l += h[q] * W2[q * NCLS + j];
        logits[j] = l;
    }
    __syncthreads();
    if (j == 0) {
        float m = -INFINITY;
        for (int o = 0; o < NCLS; o++) m = fmaxf(m, logits[o]);
        float s = 0.f;
        for (int o = 0; o < NCLS; o++) s += expf(logits[o] - m);
        mstat[0] = m;
        mstat[1] = logf(s);
    }
    __syncthreads();
    if (j < NCLS) out[g * NCLS + j] = logits[j] - mstat[0] - mstat[1];
}

// ---------------------------------------------------------------------------
extern "C" void kernel_launch(void* const* d_in, const int* in_sizes, int n_in,
                              void* d_out, int out_size, void* d_ws, size_t ws_size,
                              hipStream_t stream) {
    const float* pos   = (const float*)d_in[0];
    const float* Wsp   = (const float*)d_in[1];
    const float* root  = (const float*)d_in[2];
    const float* bias  = (const float*)d_in[3];
    const float* gamma = (const float*)d_in[4];
    const float* beta  = (const float*)d_in[5];
    const float* W1    = (const float*)d_in[6];
    const float* b1    = (const float*)d_in[7];
    const float* W2    = (const float*)d_in[8];
    const float* b2    = (const float*)d_in[9];
    float* out = (float*)d_out;

    char* ws = (char*)d_ws;
    int* nbr    = (int*)(ws);                      // 32768*20*4   = 2621440 B
    float* node = (float*)(ws + 2621440);          // 32768*32*4   = 4194304 B
    float* v3   = (float*)(ws + 6815744);          // 32768*3*4    = 393216 B
    float* sums = (float*)(ws + 7208960);          // 64*4         = 256 B
    float* ys   = (float*)(ws + 7209216);          // 24*32*4      = 3072 B

    // zero sums (256 B) + ys (3072 B) in one contiguous memset
    hipMemsetAsync(sums, 0, 3328, stream);

    knn_kernel<<<512, 256, 0, stream>>>(pos, nbr);
    point_kernel<<<256, 128, 0, stream>>>(pos, nbr, Wsp, root, bias, node, v3);
    bn_stats_kernel<<<128, 256, 0, stream>>>(node, sums);
    ys_kernel<<<NGROUP * YSPLIT, 256, 0, stream>>>(node, v3, sums, gamma, beta, ys);
    head_kernel<<<NGROUP, 256, 0, stream>>>(ys, W1, b1, W2, b2, out);
}

// Round 5
// 342.450 us; speedup vs baseline: 7.7878x; 1.3813x over previous
//
#include <hip/hip_runtime.h>
#include <hip/hip_bf16.h>
#include <math.h>

// Problem constants
#define BGR 8        // graphs
#define PP 4096      // points per graph
#define NPTS 32768   // B*P
#define KNN 20
#define LCOV 10
#define FF 32
#define KS 5
#define NCLS 40
#define NGROUP 24    // 3*B, rows of ys
#define GROUPLEN 131072  // P*F flat elements per group

// KNN tiling: 512 blocks = 64 blocks/graph; 256 thr = 64 pts x 4 range-quarters
#define SPLIT 4
#define CHUNK (PP / SPLIT)        // 1024 candidates per thread
#define PTSBLK 64                 // points per block
#define CAP 4                     // per-lane candidate buffer
#define NSLOT (KNN + 1)           // 21: slot 0 absorbs the self-point (d=0)
#define MPAD (KNN + 1)            // merge-list stride 21: gcd(21,32)=1, no conflicts

// ---------------------------------------------------------------------------
// Kernel 1: brute-force KNN per graph — PACKED-KEY top-k.
// key = (float_bits(d) & ~0xFFF) | j   (d >= 0 so uint order == float order;
// graph-local j fits the 12 truncated mantissa bits exactly). One uint per
// candidate; insertion network stage = v_min_u32 + v_max_u32 (2 ops). Ties in
// truncated distance resolve toward lower index = jax.lax.top_k semantics.
// Self-point: d=0 -> key=li < any real key -> always lands in slot 0 of the
// 21-slot network; final answer = slots 1..20. No j!=li test in the hot loop.
// Truncation (2^-12 relative) can only swap near-degenerate neighbors;
// impact on the averaged output is far below the 9.25e-2 threshold.
// ---------------------------------------------------------------------------
__device__ inline unsigned umn(unsigned a, unsigned b) { return a < b ? a : b; }
__device__ inline unsigned umx(unsigned a, unsigned b) { return a > b ? a : b; }

__global__ __launch_bounds__(256) void knn_kernel(const float* __restrict__ pos,
                                                  int* __restrict__ nbr) {
    __shared__ float smem[3 * PP];   // 48 KB arena
    float* sx = smem;
    float* sy = smem + PP;
    float* sz = smem + 2 * PP;

    int b = blockIdx.x >> 6;          // 64 blocks per graph
    int blkInGraph = blockIdx.x & 63;
    const float* gp = pos + (size_t)b * PP * 3;
    for (int i = threadIdx.x; i < PP; i += 256) {
        sx[i] = gp[i * 3 + 0];
        sy[i] = gp[i * 3 + 1];
        sz[i] = gp[i * 3 + 2];
    }
    __syncthreads();

    int quarter = threadIdx.x >> 6;       // 0..3 (one wave per quarter)
    int pt = threadIdx.x & (PTSBLK - 1);  // 0..63
    int li = blkInGraph * PTSBLK + pt;    // local point index in graph
    float px = sx[li], py = sy[li], pz = sz[li];

    unsigned bd[NSLOT];
#pragma unroll
    for (int k = 0; k < NSLOT; k++) bd[k] = 0xFFFFFFFFu;
    unsigned worst = 0xFFFFFFFFu;

    unsigned bufk[CAP];
    int cnt = 0;
#pragma unroll
    for (int s = 0; s < CAP; s++) bufk[s] = 0xFFFFFFFFu;

    auto flush = [&]() {
#pragma unroll
        for (int s = 0; s < CAP; s++) {
            unsigned k = bufk[s];
#pragma unroll
            for (int i = 0; i < NSLOT; i++) {
                unsigned lo = umn(k, bd[i]);   // v_min_u32
                k = umx(k, bd[i]);             // v_max_u32
                bd[i] = lo;
            }
            bufk[s] = 0xFFFFFFFFu;
        }
        cnt = 0;
        worst = bd[NSLOT - 1];
    };

    int jbeg = quarter * CHUNK;
    int jend = jbeg + CHUNK;
    for (int j = jbeg; j < jend; ++j) {
        float dx = px - sx[j];
        float dy = py - sy[j];
        float dz = pz - sz[j];
        float d = dx * dx;
        d = fmaf(dy, dy, d);
        d = fmaf(dz, dz, d);
        unsigned key = (__float_as_uint(d) & 0xFFFFF000u) | (unsigned)j;
        if (key < worst) {
#pragma unroll
            for (int s = 0; s < CAP; s++) bufk[s] = (cnt == s) ? key : bufk[s];
            cnt++;
        }
        if (__any(cnt >= CAP)) flush();
    }
    flush();

    // ---- merge the four quarter-range sorted lists per point via LDS ----
    // Keys are self-describing (index embedded), so one uint array suffices.
    // Stride MPAD=21 -> gcd(21,32)=1 -> conflict-free lane spread.
    // mk needs 4*64*21 = 5376 words <= 12288 arena words. No aliasing.
    __syncthreads();
    unsigned* mk = (unsigned*)smem;
#pragma unroll
    for (int k = 0; k < KNN; k++)
        mk[(quarter * PTSBLK + pt) * MPAD + k] = bd[k + 1];  // drop self slot 0
    __syncthreads();
    if (threadIdx.x < PTSBLK) {
        int p = threadIdx.x;
        const unsigned* A = &mk[(0 * PTSBLK + p) * MPAD];
        const unsigned* B = &mk[(1 * PTSBLK + p) * MPAD];
        const unsigned* C = &mk[(2 * PTSBLK + p) * MPAD];
        const unsigned* D = &mk[(3 * PTSBLK + p) * MPAD];
        int ia = 0, ib = 0, ic = 0, id = 0;
        int gi = b * PP + blkInGraph * PTSBLK + p;
        // No sentinels needed: a cursor can only reach 20 after 20 picks,
        // i.e. after the loop has already terminated (reads stay in-bounds).
#pragma unroll
        for (int k = 0; k < KNN; k++) {
            unsigned va = A[ia];
            unsigned vb = B[ib];
            unsigned vc = C[ic];
            unsigned vd = D[id];
            unsigned m = umn(umn(va, vb), umn(vc, vd));
            nbr[gi * KNN + k] = b * PP + (int)(m & 0xFFFu);
            ia += (va == m);
            ib += (vb == m);
            ic += (vc == m);
            id += (vd == m);
        }
    }
}

// ---------------------------------------------------------------------------
// 3x3 helpers + power iteration (replicates reference arithmetic)
// ---------------------------------------------------------------------------
__device__ inline void mat3vec(const float M[9], const float v[3], float w[3]) {
    w[0] = M[0] * v[0] + M[1] * v[1] + M[2] * v[2];
    w[1] = M[3] * v[0] + M[4] * v[1] + M[5] * v[2];
    w[2] = M[6] * v[0] + M[7] * v[1] + M[8] * v[2];
}

__device__ inline float pi3(const float M[9], float v[3]) {
    v[0] = v[1] = v[2] = 0.57735026918962576f;  // 3^-0.5 as f32
#pragma unroll
    for (int it = 0; it < 5; ++it) {
        float w[3];
        mat3vec(M, v, w);
        float nrm = sqrtf(w[0] * w[0] + w[1] * w[1] + w[2] * w[2]) + 1e-12f;
        v[0] = w[0] / nrm;
        v[1] = w[1] / nrm;
        v[2] = w[2] / nrm;
    }
    float w[3];
    mat3vec(M, v, w);
    return v[0] * w[0] + v[1] * w[1] + v[2] * w[2];
}

// ---------------------------------------------------------------------------
// Kernel 2: per-point cov -> eig -> dirc -> spline conv -> node features.
// 256 blocks x 128 threads (fills all 256 CUs).
// Wsp staged in LDS transposed [f][flat] (stride 125) to spread LDS banks.
// ---------------------------------------------------------------------------
__global__ __launch_bounds__(128) void point_kernel(
    const float* __restrict__ pos, const int* __restrict__ nbr,
    const float* __restrict__ Wsp, const float* __restrict__ root,
    const float* __restrict__ bias, float* __restrict__ node,
    float* __restrict__ v3out) {
    __shared__ float sWt[FF * 125];  // [f][flat]
    for (int i = threadIdx.x; i < FF * 125; i += 128) {
        int f = i / 125;
        int j = i - f * 125;
        sWt[i] = Wsp[j * FF + f];
    }
    __syncthreads();

    int n = blockIdx.x * 128 + threadIdx.x;
    float px = pos[n * 3 + 0], py = pos[n * 3 + 1], pz = pos[n * 3 + 2];

    float cx[KNN], cy[KNN], cz[KNN];
#pragma unroll
    for (int k = 0; k < KNN; k++) {
        int id = nbr[n * KNN + k];
        cx[k] = pos[id * 3 + 0] - px;
        cy[k] = pos[id * 3 + 1] - py;
        cz[k] = pos[id * 3 + 2] - pz;
    }

    // covariance over the L nearest
    float M[9] = {0.f, 0.f, 0.f, 0.f, 0.f, 0.f, 0.f, 0.f, 0.f};
#pragma unroll
    for (int m = 0; m < LCOV; m++) {
        M[0] += cx[m] * cx[m];
        M[1] += cx[m] * cy[m];
        M[2] += cx[m] * cz[m];
        M[4] += cy[m] * cy[m];
        M[5] += cy[m] * cz[m];
        M[8] += cz[m] * cz[m];
    }
    M[3] = M[1];
    M[6] = M[2];
    M[7] = M[5];

    float v1[3], v2[3], v3[3];
    float l1 = pi3(M, v1);
    float M2[9];
#pragma unroll
    for (int c = 0; c < 3; c++)
#pragma unroll
        for (int d = 0; d < 3; d++) M2[c * 3 + d] = M[c * 3 + d] - l1 * v1[c] * v1[d];
    pi3(M2, v2);
    // v3 = normalize(cross(v1, v2))
    v3[0] = v1[1] * v2[2] - v1[2] * v2[1];
    v3[1] = v1[2] * v2[0] - v1[0] * v2[2];
    v3[2] = v1[0] * v2[1] - v1[1] * v2[0];
    {
        float nrm = sqrtf(v3[0] * v3[0] + v3[1] * v3[1] + v3[2] * v3[2]) + 1e-12f;
        v3[0] /= nrm;
        v3[1] /= nrm;
        v3[2] /= nrm;
    }

    // pass 1 over neighbors: sign accumulator + max_abs
    float ssum = 0.f, mx = 0.f;
#pragma unroll
    for (int k = 0; k < KNN; k++) {
        float d0 = cx[k] * v1[0] + cy[k] * v1[1] + cz[k] * v1[2];
        float d1 = cx[k] * v2[0] + cy[k] * v2[1] + cz[k] * v2[2];
        float d2 = cx[k] * v3[0] + cy[k] * v3[1] + cz[k] * v3[2];
        ssum += d2;
        mx = fmaxf(mx, fabsf(d0));
        mx = fmaxf(mx, fabsf(d1));
        mx = fmaxf(mx, fabsf(d2));
    }
    float sgn = (ssum > 0.f) ? 1.f : ((ssum < 0.f) ? -1.f : 0.f);

    // pass 2: spline conv accumulate
    float msg[FF];
#pragma unroll
    for (int f = 0; f < FF; f++) msg[f] = 0.f;

#pragma unroll
    for (int k = 0; k < KNN; k++) {
        float d0 = cx[k] * v1[0] + cy[k] * v1[1] + cz[k] * v1[2];
        float d1 = cx[k] * v2[0] + cy[k] * v2[1] + cz[k] * v2[2];
        float d2 = cx[k] * v3[0] + cy[k] * v3[1] + cz[k] * v3[2];
        d2 *= sgn;
        float u0 = d0 / mx * 0.5f + 0.5f;
        float u1 = d1 / mx * 0.5f + 0.5f;
        float u2 = d2 / mx * 0.5f + 0.5f;
        float vv0 = u0 * (KS - 1), vv1 = u1 * (KS - 1), vv2 = u2 * (KS - 1);
        float f0 = floorf(vv0), f1 = floorf(vv1), f2 = floorf(vv2);
        float fr0 = vv0 - f0, fr1 = vv1 - f1, fr2 = vv2 - f2;
        int fi0 = (int)f0, fi1 = (int)f1, fi2 = (int)f2;
#pragma unroll
        for (int s = 0; s < 8; s++) {
            int b0 = (s >> 2) & 1, b1 = (s >> 1) & 1, b2s = s & 1;
            int i0 = fi0 + b0; i0 = i0 > KS - 1 ? KS - 1 : i0;
            int i1 = fi1 + b1; i1 = i1 > KS - 1 ? KS - 1 : i1;
            int i2 = fi2 + b2s; i2 = i2 > KS - 1 ? KS - 1 : i2;
            float w = (b0 ? fr0 : 1.f - fr0) * (b1 ? fr1 : 1.f - fr1) *
                      (b2s ? fr2 : 1.f - fr2);
            int flat = (i0 * KS + i1) * KS + i2;
#pragma unroll
            for (int f = 0; f < FF; f++) msg[f] += w * sWt[f * 125 + flat];
        }
    }

#pragma unroll
    for (int f = 0; f < FF; f++)
        node[(size_t)n * FF + f] = msg[f] * (1.0f / KNN) + root[f] + bias[f];
    v3out[n * 3 + 0] = v3[0];
    v3out[n * 3 + 1] = v3[1];
    v3out[n * 3 + 2] = v3[2];
}

// ---------------------------------------------------------------------------
// Kernel 3: batch-norm statistics (sum, sumsq per feature) via atomics.
// ---------------------------------------------------------------------------
__global__ __launch_bounds__(256) void bn_stats_kernel(const float* __restrict__ node,
                                                       float* __restrict__ sums) {
    __shared__ float ls[256];
    __shared__ float ls2[256];
    float s = 0.f, s2 = 0.f;
    int total = NPTS * FF;
    for (int i = blockIdx.x * 256 + threadIdx.x; i < total; i += gridDim.x * 256) {
        float x = node[i];
        s += x;
        s2 += x * x;
    }
    ls[threadIdx.x] = s;
    ls2[threadIdx.x] = s2;
    __syncthreads();
    if (threadIdx.x < FF) {
        float a = 0.f, b = 0.f;
        for (int t = threadIdx.x; t < 256; t += FF) {
            a += ls[t];
            b += ls2[t];
        }
        atomicAdd(&sums[threadIdx.x], a);
        atomicAdd(&sums[FF + threadIdx.x], b);
    }
}

// ---------------------------------------------------------------------------
// Kernel 4: apply BN, scale normal, sigmoid, reduce to ys (24, 32).
// Grid 24 groups x 8 p-range splits = 192 blocks; partials via atomicAdd
// into zeroed ys. Bucket invariant: i-range offsets are multiples of 32, so
// thread tid always accumulates feature f2 = tid & 31.
// ---------------------------------------------------------------------------
#define YSPLIT 8
#define YCHUNK (GROUPLEN / YSPLIT)   // 16384
__global__ __launch_bounds__(256) void ys_kernel(
    const float* __restrict__ node, const float* __restrict__ v3,
    const float* __restrict__ sums, const float* __restrict__ gamma,
    const float* __restrict__ beta, float* __restrict__ ys) {
    __shared__ float sa[FF], sb[FF];
    if (threadIdx.x < FF) {
        int f = threadIdx.x;
        float mu = sums[f] * (1.0f / NPTS);
        float var = sums[FF + f] * (1.0f / NPTS) - mu * mu;
        float inv = 1.0f / sqrtf(var + 1e-5f);
        sa[f] = gamma[f] * inv;
        sb[f] = beta[f] - gamma[f] * inv * mu;
    }
    __syncthreads();

    int g = blockIdx.x >> 3;
    int sub = blockIdx.x & 7;
    float acc = 0.f;
    int ibeg = sub * YCHUNK + threadIdx.x;
    int iend = (sub + 1) * YCHUNK;
    for (int i = ibeg; i < iend; i += 256) {
        int t = g * GROUPLEN + i;
        int n = t / 96;
        int r = t - n * 96;
        int f = r / 3;
        int c = r - f * 3;
        float xb = sa[f] * node[(size_t)n * FF + f] + sb[f];
        float val = xb * v3[n * 3 + c];
        acc += 1.0f / (1.0f + expf(-val));
    }
    __shared__ float red[256];
    red[threadIdx.x] = acc;
    __syncthreads();
    if (threadIdx.x < FF) {
        float s = 0.f;
        for (int t = threadIdx.x; t < 256; t += FF) s += red[t];
        atomicAdd(&ys[g * FF + threadIdx.x], s * (1.0f / PP));
    }
}

// ---------------------------------------------------------------------------
// Kernel 5: tiny MLP head: elu(ys@W1+b1) @ W2 + b2 -> log_softmax. 1 block/row.
// ---------------------------------------------------------------------------
__global__ __launch_bounds__(256) void head_kernel(
    const float* __restrict__ ys, const float* __restrict__ W1,
    const float* __restrict__ b1, const float* __restrict__ W2,
    const float* __restrict__ b2, float* __restrict__ out) {
    int g = blockIdx.x;
    __shared__ float syr[FF];
    __shared__ float h[256];
    __shared__ float logits[NCLS];
    __shared__ float mstat[2];
    if (threadIdx.x < FF) syr[threadIdx.x] = ys[g * FF + threadIdx.x];
    __syncthreads();
    int j = threadIdx.x;
    float acc = b1[j];
#pragma unroll
    for (int f = 0; f < FF; f++) acc += syr[f] * W1[f * 256 + j];
    h[j] = acc > 0.f ? acc : expm1f(acc);
    __syncthreads();
    if (j < NCLS) {
        float l = b2[j];
        for (int q = 0; q < 256; q++) l += h[q] * W2[q * NCLS + j];
        logits[j] = l;
    }
    __syncthreads();
    if (j == 0) {
        float m = -INFINITY;
        for (int o = 0; o < NCLS; o++) m = fmaxf(m, logits[o]);
        float s = 0.f;
        for (int o = 0; o < NCLS; o++) s += expf(logits[o] - m);
        mstat[0] = m;
        mstat[1] = logf(s);
    }
    __syncthreads();
    if (j < NCLS) out[g * NCLS + j] = logits[j] - mstat[0] - mstat[1];
}

// ---------------------------------------------------------------------------
extern "C" void kernel_launch(void* const* d_in, const int* in_sizes, int n_in,
                              void* d_out, int out_size, void* d_ws, size_t ws_size,
                              hipStream_t stream) {
    const float* pos   = (const float*)d_in[0];
    const float* Wsp   = (const float*)d_in[1];
    const float* root  = (const float*)d_in[2];
    const float* bias  = (const float*)d_in[3];
    const float* gamma = (const float*)d_in[4];
    const float* beta  = (const float*)d_in[5];
    const float* W1    = (const float*)d_in[6];
    const float* b1    = (const float*)d_in[7];
    const float* W2    = (const float*)d_in[8];
    const float* b2    = (const float*)d_in[9];
    float* out = (float*)d_out;

    char* ws = (char*)d_ws;
    int* nbr    = (int*)(ws);                      // 32768*20*4   = 2621440 B
    float* node = (float*)(ws + 2621440);          // 32768*32*4   = 4194304 B
    float* v3   = (float*)(ws + 6815744);          // 32768*3*4    = 393216 B
    float* sums = (float*)(ws + 7208960);          // 64*4         = 256 B
    float* ys   = (float*)(ws + 7209216);          // 24*32*4      = 3072 B

    // zero sums (256 B) + ys (3072 B) in one contiguous memset
    hipMemsetAsync(sums, 0, 3328, stream);

    knn_kernel<<<512, 256, 0, stream>>>(pos, nbr);
    point_kernel<<<256, 128, 0, stream>>>(pos, nbr, Wsp, root, bias, node, v3);
    bn_stats_kernel<<<128, 256, 0, stream>>>(node, sums);
    ys_kernel<<<NGROUP * YSPLIT, 256, 0, stream>>>(node, v3, sums, gamma, beta, ys);
    head_kernel<<<NGROUP, 256, 0, stream>>>(ys, W1, b1, W2, b2, out);
}

// Round 6
// 317.850 us; speedup vs baseline: 8.3905x; 1.0774x over previous
//
#include <hip/hip_runtime.h>
#include <hip/hip_bf16.h>
#include <math.h>

// Problem constants
#define BGR 8        // graphs
#define PP 4096      // points per graph
#define NPTS 32768   // B*P
#define KNN 20
#define LCOV 10
#define FF 32
#define KS 5
#define NCLS 40
#define NGROUP 24    // 3*B, rows of ys
#define GROUPLEN 131072  // P*F flat elements per group

// KNN tiling: 512 blocks x 512 threads; thread = (eighth 0..7, pt 0..63)
#define SPLIT 8
#define CHUNK (PP / SPLIT)        // 512 candidates per thread
#define PTSBLK 64                 // points per block
#define KTHR (SPLIT * PTSBLK)     // 512 threads
#define CAP 4                     // per-lane candidate buffer
#define NSLOT (KNN + 1)           // 21-slot network (self-point absorbable)
#define MPAD NSLOT                // merge-list stride 21: gcd(21,32)=1

// ---------------------------------------------------------------------------
// Kernel 1: brute-force KNN per graph — PACKED-KEY top-k.
// key = (float_bits(d) & ~0xFFF) | j  (d>=0 -> uint order == float order; the
// graph-local j fits the 12 truncated bits). Insertion-network stage =
// v_min_u32 + v_max_u32. Keys are UNIQUE (index embedded) so merge order is
// total and ties resolve toward lower index = jax.lax.top_k semantics.
//
// R5 BUG FIX: each eighth stores ALL 21 slots; the self key (= li, globally
// the minimum since d=0) is skipped as the FIRST pick of the 8-way merge.
// (R5 dropped slot 0 of every list, losing the best real neighbor of the 7
// lists not containing the self-point.)
// ---------------------------------------------------------------------------
__device__ inline unsigned umn(unsigned a, unsigned b) { return a < b ? a : b; }
__device__ inline unsigned umx(unsigned a, unsigned b) { return a > b ? a : b; }

__global__ __launch_bounds__(KTHR) void knn_kernel(const float* __restrict__ pos,
                                                   int* __restrict__ nbr) {
    __shared__ float smem[3 * PP];   // 48 KB arena
    float* sx = smem;
    float* sy = smem + PP;
    float* sz = smem + 2 * PP;

    int b = blockIdx.x >> 6;          // 64 blocks per graph
    int blkInGraph = blockIdx.x & 63;
    const float* gp = pos + (size_t)b * PP * 3;
    for (int i = threadIdx.x; i < PP; i += KTHR) {
        sx[i] = gp[i * 3 + 0];
        sy[i] = gp[i * 3 + 1];
        sz[i] = gp[i * 3 + 2];
    }
    __syncthreads();

    int eighth = threadIdx.x >> 6;        // 0..7 (one wave per eighth)
    int pt = threadIdx.x & (PTSBLK - 1);  // 0..63
    int li = blkInGraph * PTSBLK + pt;    // local point index in graph
    float px = sx[li], py = sy[li], pz = sz[li];

    unsigned bd[NSLOT];
#pragma unroll
    for (int k = 0; k < NSLOT; k++) bd[k] = 0xFFFFFFFFu;
    unsigned worst = 0xFFFFFFFFu;

    unsigned bufk[CAP];
    int cnt = 0;
#pragma unroll
    for (int s = 0; s < CAP; s++) bufk[s] = 0xFFFFFFFFu;

    auto flush = [&]() {
#pragma unroll
        for (int s = 0; s < CAP; s++) {
            unsigned k = bufk[s];
#pragma unroll
            for (int i = 0; i < NSLOT; i++) {
                unsigned lo = umn(k, bd[i]);   // v_min_u32
                k = umx(k, bd[i]);             // v_max_u32
                bd[i] = lo;
            }
            bufk[s] = 0xFFFFFFFFu;
        }
        cnt = 0;
        worst = bd[NSLOT - 1];
    };

    int jbeg = eighth * CHUNK;
    int jend = jbeg + CHUNK;
    for (int j = jbeg; j < jend; ++j) {
        float dx = px - sx[j];
        float dy = py - sy[j];
        float dz = pz - sz[j];
        float d = dx * dx;
        d = fmaf(dy, dy, d);
        d = fmaf(dz, dz, d);
        unsigned key = (__float_as_uint(d) & 0xFFFFF000u) | (unsigned)j;
        if (key < worst) {
#pragma unroll
            for (int s = 0; s < CAP; s++) bufk[s] = (cnt == s) ? key : bufk[s];
            cnt++;
        }
        if (__any(cnt >= CAP)) flush();
    }
    flush();

    // ---- 8-way merge of 21-long sorted lists per point via LDS ----
    // mk needs 8*64*21 = 10752 words <= 12288 arena words.
    __syncthreads();
    unsigned* mk = (unsigned*)smem;
#pragma unroll
    for (int k = 0; k < NSLOT; k++)
        mk[(eighth * PTSBLK + pt) * MPAD + k] = bd[k];
    __syncthreads();
    if (threadIdx.x < PTSBLK) {
        int p = threadIdx.x;
        const unsigned* base = &mk[p * MPAD];
        int cur[SPLIT];
#pragma unroll
        for (int q = 0; q < SPLIT; q++) cur[q] = 0;
        int gi = b * PP + blkInGraph * PTSBLK + p;
        // 21 picks; pick 0 is provably the self key (d=0 -> key=li < any
        // real key) and is skipped. Cursor reads stay within slots 0..20.
#pragma unroll
        for (int t = 0; t < NSLOT; t++) {
            unsigned v[SPLIT];
#pragma unroll
            for (int q = 0; q < SPLIT; q++)
                v[q] = base[q * PTSBLK * MPAD + cur[q]];
            unsigned m = v[0];
#pragma unroll
            for (int q = 1; q < SPLIT; q++) m = umn(m, v[q]);
            if (t > 0) nbr[gi * KNN + (t - 1)] = b * PP + (int)(m & 0xFFFu);
#pragma unroll
            for (int q = 0; q < SPLIT; q++) cur[q] += (v[q] == m);
        }
    }
}

// ---------------------------------------------------------------------------
// 3x3 helpers + power iteration (replicates reference arithmetic)
// ---------------------------------------------------------------------------
__device__ inline void mat3vec(const float M[9], const float v[3], float w[3]) {
    w[0] = M[0] * v[0] + M[1] * v[1] + M[2] * v[2];
    w[1] = M[3] * v[0] + M[4] * v[1] + M[5] * v[2];
    w[2] = M[6] * v[0] + M[7] * v[1] + M[8] * v[2];
}

__device__ inline float pi3(const float M[9], float v[3]) {
    v[0] = v[1] = v[2] = 0.57735026918962576f;  // 3^-0.5 as f32
#pragma unroll
    for (int it = 0; it < 5; ++it) {
        float w[3];
        mat3vec(M, v, w);
        float nrm = sqrtf(w[0] * w[0] + w[1] * w[1] + w[2] * w[2]) + 1e-12f;
        v[0] = w[0] / nrm;
        v[1] = w[1] / nrm;
        v[2] = w[2] / nrm;
    }
    float w[3];
    mat3vec(M, v, w);
    return v[0] * w[0] + v[1] * w[1] + v[2] * w[2];
}

// ---------------------------------------------------------------------------
// Kernel 2a: per-point eigen stage. Writes v3 (unsigned normal, for ys) and
// prescaled rows R: spline coord v_c = c . R_c + 2, where
// R_c = eigvec_c * (2/mx) * (c==2 ? sgn : 1). Stride 12 floats (48B aligned).
// ---------------------------------------------------------------------------
__global__ __launch_bounds__(256) void eig_kernel(
    const float* __restrict__ pos, const int* __restrict__ nbr,
    float* __restrict__ Rbuf, float* __restrict__ v3out) {
    int n = blockIdx.x * 256 + threadIdx.x;
    float px = pos[n * 3 + 0], py = pos[n * 3 + 1], pz = pos[n * 3 + 2];

    float cx[KNN], cy[KNN], cz[KNN];
#pragma unroll
    for (int k = 0; k < KNN; k++) {
        int id = nbr[n * KNN + k];
        cx[k] = pos[id * 3 + 0] - px;
        cy[k] = pos[id * 3 + 1] - py;
        cz[k] = pos[id * 3 + 2] - pz;
    }

    float M[9] = {0.f, 0.f, 0.f, 0.f, 0.f, 0.f, 0.f, 0.f, 0.f};
#pragma unroll
    for (int m = 0; m < LCOV; m++) {
        M[0] += cx[m] * cx[m];
        M[1] += cx[m] * cy[m];
        M[2] += cx[m] * cz[m];
        M[4] += cy[m] * cy[m];
        M[5] += cy[m] * cz[m];
        M[8] += cz[m] * cz[m];
    }
    M[3] = M[1];
    M[6] = M[2];
    M[7] = M[5];

    float v1[3], v2[3], v3[3];
    float l1 = pi3(M, v1);
    float M2[9];
#pragma unroll
    for (int c = 0; c < 3; c++)
#pragma unroll
        for (int d = 0; d < 3; d++) M2[c * 3 + d] = M[c * 3 + d] - l1 * v1[c] * v1[d];
    pi3(M2, v2);
    v3[0] = v1[1] * v2[2] - v1[2] * v2[1];
    v3[1] = v1[2] * v2[0] - v1[0] * v2[2];
    v3[2] = v1[0] * v2[1] - v1[1] * v2[0];
    {
        float nrm = sqrtf(v3[0] * v3[0] + v3[1] * v3[1] + v3[2] * v3[2]) + 1e-12f;
        v3[0] /= nrm;
        v3[1] /= nrm;
        v3[2] /= nrm;
    }

    float ssum = 0.f, mx = 0.f;
#pragma unroll
    for (int k = 0; k < KNN; k++) {
        float d0 = cx[k] * v1[0] + cy[k] * v1[1] + cz[k] * v1[2];
        float d1 = cx[k] * v2[0] + cy[k] * v2[1] + cz[k] * v2[2];
        float d2 = cx[k] * v3[0] + cy[k] * v3[1] + cz[k] * v3[2];
        ssum += d2;
        mx = fmaxf(mx, fabsf(d0));
        mx = fmaxf(mx, fabsf(d1));
        mx = fmaxf(mx, fabsf(d2));
    }
    float sgn = (ssum > 0.f) ? 1.f : ((ssum < 0.f) ? -1.f : 0.f);

    float sc = 2.0f / mx;
    float* R = Rbuf + (size_t)n * 12;
    R[0] = v1[0] * sc;  R[1] = v1[1] * sc;  R[2] = v1[2] * sc;
    R[3] = v2[0] * sc;  R[4] = v2[1] * sc;  R[5] = v2[2] * sc;
    float s2 = sgn * sc;
    R[6] = v3[0] * s2;  R[7] = v3[1] * s2;  R[8] = v3[2] * s2;
    R[9] = 0.f; R[10] = 0.f; R[11] = 0.f;

    v3out[n * 3 + 0] = v3[0];
    v3out[n * 3 + 1] = v3[1];
    v3out[n * 3 + 2] = v3[2];
}

// ---------------------------------------------------------------------------
// Kernel 2b: spline conv. Block = 512 threads = 16 points.
// Phase 1 (320 threads = pt x k): basis weights; flat index packed into the
// low 7 mantissa bits of w (<=2^-16 perturbation) -> one LDS word per (k,s).
// Phase 2 (512 threads = pt x f): msg[f] = sum over 160 of w * sWt[f][flat].
// sWt transposed [f][flat] stride 125 (gcd(125,32)=1 -> conflict-free).
// LDS: 16000B sWt + 10240B wbuf = 25.7KB -> 4 blocks/CU (wave-capped).
// ---------------------------------------------------------------------------
#define NPB 16
__global__ __launch_bounds__(512) void spline_kernel(
    const float* __restrict__ pos, const int* __restrict__ nbr,
    const float* __restrict__ Rbuf, const float* __restrict__ Wsp,
    const float* __restrict__ root, const float* __restrict__ bias,
    float* __restrict__ node) {
    __shared__ float sWt[FF * 125];          // [f][flat]
    __shared__ float wbuf[NPB * KNN * 8];    // packed w' per (pt,k,s)
    for (int i = threadIdx.x; i < FF * 125; i += 512) {
        int f = i / 125;
        int j = i - f * 125;
        sWt[i] = Wsp[j * FF + f];
    }

    int tid = threadIdx.x;
    if (tid < NPB * KNN) {              // 320 phase-1 threads
        int pt = tid / KNN;
        int k = tid - pt * KNN;
        int n = blockIdx.x * NPB + pt;
        const float4* Rv = (const float4*)(Rbuf + (size_t)n * 12);
        float4 r0 = Rv[0], r1 = Rv[1], r2 = Rv[2];
        float px = pos[n * 3 + 0], py = pos[n * 3 + 1], pz = pos[n * 3 + 2];
        int id = nbr[n * KNN + k];
        float cxx = pos[id * 3 + 0] - px;
        float cyy = pos[id * 3 + 1] - py;
        float czz = pos[id * 3 + 2] - pz;
        // v_c = c . R_c + 2   (rows packed: R0=r0.xyz, R1=(r0.w,r1.x,r1.y),
        // R2=(r1.z,r1.w,r2.x))
        float v0 = fmaf(cxx, r0.x, fmaf(cyy, r0.y, fmaf(czz, r0.z, 2.0f)));
        float v1 = fmaf(cxx, r0.w, fmaf(cyy, r1.x, fmaf(czz, r1.y, 2.0f)));
        float v2 = fmaf(cxx, r1.z, fmaf(cyy, r1.w, fmaf(czz, r2.x, 2.0f)));
        float f0 = floorf(v0), f1 = floorf(v1), f2 = floorf(v2);
        float fr0 = v0 - f0, fr1 = v1 - f1, fr2 = v2 - f2;
        int fi0 = (int)f0, fi1 = (int)f1, fi2 = (int)f2;
        float* wdst = &wbuf[(pt * KNN + k) * 8];
#pragma unroll
        for (int s = 0; s < 8; s++) {
            int b0 = (s >> 2) & 1, b1 = (s >> 1) & 1, b2s = s & 1;
            // clamp BOTH sides: refactored arithmetic can give v just
            // outside [0,4] (boundary weight ~0, so clamping is exact).
            int i0 = min(max(fi0 + b0, 0), KS - 1);
            int i1 = min(max(fi1 + b1, 0), KS - 1);
            int i2 = min(max(fi2 + b2s, 0), KS - 1);
            float w = (b0 ? fr0 : 1.f - fr0) * (b1 ? fr1 : 1.f - fr1) *
                      (b2s ? fr2 : 1.f - fr2);
            unsigned flat = (unsigned)((i0 * KS + i1) * KS + i2);
            wdst[s] = __uint_as_float((__float_as_uint(w) & ~127u) | flat);
        }
    }
    __syncthreads();

    // phase 2: thread = (pt, f)
    int pt = tid >> 5;
    int f = tid & 31;
    const float* wrow = &wbuf[pt * (KNN * 8)];
    const float* srow = &sWt[f * 125];
    float acc = 0.f;
#pragma unroll
    for (int k = 0; k < KNN; k++) {
        float4 wa = *(const float4*)&wrow[k * 8];
        float4 wb = *(const float4*)&wrow[k * 8 + 4];
        float wv[8] = {wa.x, wa.y, wa.z, wa.w, wb.x, wb.y, wb.z, wb.w};
#pragma unroll
        for (int s = 0; s < 8; s++) {
            unsigned u = __float_as_uint(wv[s]) & 127u;
            acc = fmaf(wv[s], srow[u], acc);
        }
    }
    int n = blockIdx.x * NPB + pt;
    node[(size_t)n * FF + f] = acc * (1.0f / KNN) + root[f] + bias[f];
}

// ---------------------------------------------------------------------------
// Kernel 3: batch-norm statistics (sum, sumsq per feature) via atomics.
// ---------------------------------------------------------------------------
__global__ __launch_bounds__(256) void bn_stats_kernel(const float* __restrict__ node,
                                                       float* __restrict__ sums) {
    __shared__ float ls[256];
    __shared__ float ls2[256];
    float s = 0.f, s2 = 0.f;
    int total = NPTS * FF;
    for (int i = blockIdx.x * 256 + threadIdx.x; i < total; i += gridDim.x * 256) {
        float x = node[i];
        s += x;
        s2 += x * x;
    }
    ls[threadIdx.x] = s;
    ls2[threadIdx.x] = s2;
    __syncthreads();
    if (threadIdx.x < FF) {
        float a = 0.f, b = 0.f;
        for (int t = threadIdx.x; t < 256; t += FF) {
            a += ls[t];
            b += ls2[t];
        }
        atomicAdd(&sums[threadIdx.x], a);
        atomicAdd(&sums[FF + threadIdx.x], b);
    }
}

// ---------------------------------------------------------------------------
// Kernel 4: apply BN, scale normal, sigmoid, reduce to ys (24, 32).
// ---------------------------------------------------------------------------
#define YSPLIT 8
#define YCHUNK (GROUPLEN / YSPLIT)   // 16384
__global__ __launch_bounds__(256) void ys_kernel(
    const float* __restrict__ node, const float* __restrict__ v3,
    const float* __restrict__ sums, const float* __restrict__ gamma,
    const float* __restrict__ beta, float* __restrict__ ys) {
    __shared__ float sa[FF], sb[FF];
    if (threadIdx.x < FF) {
        int f = threadIdx.x;
        float mu = sums[f] * (1.0f / NPTS);
        float var = sums[FF + f] * (1.0f / NPTS) - mu * mu;
        float inv = 1.0f / sqrtf(var + 1e-5f);
        sa[f] = gamma[f] * inv;
        sb[f] = beta[f] - gamma[f] * inv * mu;
    }
    __syncthreads();

    int g = blockIdx.x >> 3;
    int sub = blockIdx.x & 7;
    float acc = 0.f;
    int ibeg = sub * YCHUNK + threadIdx.x;
    int iend = (sub + 1) * YCHUNK;
    for (int i = ibeg; i < iend; i += 256) {
        int t = g * GROUPLEN + i;
        int n = t / 96;
        int r = t - n * 96;
        int f = r / 3;
        int c = r - f * 3;
        float xb = sa[f] * node[(size_t)n * FF + f] + sb[f];
        float val = xb * v3[n * 3 + c];
        acc += 1.0f / (1.0f + expf(-val));
    }
    __shared__ float red[256];
    red[threadIdx.x] = acc;
    __syncthreads();
    if (threadIdx.x < FF) {
        float s = 0.f;
        for (int t = threadIdx.x; t < 256; t += FF) s += red[t];
        atomicAdd(&ys[g * FF + threadIdx.x], s * (1.0f / PP));
    }
}

// ---------------------------------------------------------------------------
// Kernel 5: tiny MLP head: elu(ys@W1+b1) @ W2 + b2 -> log_softmax. 1 block/row.
// ---------------------------------------------------------------------------
__global__ __launch_bounds__(256) void head_kernel(
    const float* __restrict__ ys, const float* __restrict__ W1,
    const float* __restrict__ b1, const float* __restrict__ W2,
    const float* __restrict__ b2, float* __restrict__ out) {
    int g = blockIdx.x;
    __shared__ float syr[FF];
    __shared__ float h[256];
    __shared__ float logits[NCLS];
    __shared__ float mstat[2];
    if (threadIdx.x < FF) syr[threadIdx.x] = ys[g * FF + threadIdx.x];
    __syncthreads();
    int j = threadIdx.x;
    float acc = b1[j];
#pragma unroll
    for (int f = 0; f < FF; f++) acc += syr[f] * W1[f * 256 + j];
    h[j] = acc > 0.f ? acc : expm1f(acc);
    __syncthreads();
    if (j < NCLS) {
        float l = b2[j];
        for (int q = 0; q < 256; q++) l += h[q] * W2[q * NCLS + j];
        logits[j] = l;
    }
    __syncthreads();
    if (j == 0) {
        float m = -INFINITY;
        for (int o = 0; o < NCLS; o++) m = fmaxf(m, logits[o]);
        float s = 0.f;
        for (int o = 0; o < NCLS; o++) s += expf(logits[o] - m);
        mstat[0] = m;
        mstat[1] = logf(s);
    }
    __syncthreads();
    if (j < NCLS) out[g * NCLS + j] = logits[j] - mstat[0] - mstat[1];
}

// ---------------------------------------------------------------------------
extern "C" void kernel_launch(void* const* d_in, const int* in_sizes, int n_in,
                              void* d_out, int out_size, void* d_ws, size_t ws_size,
                              hipStream_t stream) {
    const float* pos   = (const float*)d_in[0];
    const float* Wsp   = (const float*)d_in[1];
    const float* root  = (const float*)d_in[2];
    const float* bias  = (const float*)d_in[3];
    const float* gamma = (const float*)d_in[4];
    const float* beta  = (const float*)d_in[5];
    const float* W1    = (const float*)d_in[6];
    const float* b1    = (const float*)d_in[7];
    const float* W2    = (const float*)d_in[8];
    const float* b2    = (const float*)d_in[9];
    float* out = (float*)d_out;

    char* ws = (char*)d_ws;
    int* nbr    = (int*)(ws);                      // 32768*20*4   = 2621440 B
    float* node = (float*)(ws + 2621440);          // 32768*32*4   = 4194304 B
    float* v3   = (float*)(ws + 6815744);          // 32768*3*4    = 393216 B
    float* sums = (float*)(ws + 7208960);          // 64*4         = 256 B
    float* ys   = (float*)(ws + 7209216);          // 24*32*4      = 3072 B
    float* Rbuf = (float*)(ws + 7212288);          // 32768*12*4   = 1572864 B
                                                   // total 8785152 B

    // zero sums (256 B) + ys (3072 B) in one contiguous memset
    hipMemsetAsync(sums, 0, 3328, stream);

    knn_kernel<<<512, KTHR, 0, stream>>>(pos, nbr);
    eig_kernel<<<128, 256, 0, stream>>>(pos, nbr, Rbuf, v3);
    spline_kernel<<<NPTS / NPB, 512, 0, stream>>>(pos, nbr, Rbuf, Wsp, root, bias, node);
    bn_stats_kernel<<<128, 256, 0, stream>>>(node, sums);
    ys_kernel<<<NGROUP * YSPLIT, 256, 0, stream>>>(node, v3, sums, gamma, beta, ys);
    head_kernel<<<NGROUP, 256, 0, stream>>>(ys, W1, b1, W2, b2, out);
}

// Round 7
// 285.062 us; speedup vs baseline: 9.3557x; 1.1150x over previous
//
#include <hip/hip_runtime.h>
#include <hip/hip_bf16.h>
#include <math.h>

// Problem constants
#define BGR 8        // graphs
#define PP 4096      // points per graph
#define NPTS 32768   // B*P
#define KNN 20
#define LCOV 10
#define FF 32
#define KS 5
#define NCLS 40
#define NGROUP 24    // 3*B, rows of ys
#define GROUPLEN 131072  // P*F flat elements per group

// KNN tiling: 512 blocks x 512 threads; thread = (eighth 0..7, pt 0..63)
#define SPLIT 8
#define CHUNK (PP / SPLIT)        // 512 candidates per thread
#define PTSBLK 64                 // points per block
#define KTHR (SPLIT * PTSBLK)     // 512 threads
#define CAP 4                     // per-lane candidate buffer
#define NSLOT (KNN + 1)           // 21-slot network (self-point absorbable)
#define MPAD NSLOT                // merge-list stride 21: gcd(21,32)=1
#define SENT 0xFFFFFFFFu

// ---------------------------------------------------------------------------
// Kernel 1: brute-force KNN per graph — PACKED-KEY top-k, slim stream.
// key = (float_bits(d) & ~0xFFF) | j  (d>=0 -> uint order == float order).
// R7 stream cuts vs R6 (VALUBusy was 79% -> instruction count IS the wall):
//  (a) j unrolled x4 with ds_read_b128 on the wave-uniform candidate index
//      (3 vector loads replace 12 scalar loads per group),
//  (b) accept path = depth-4 shift register (4 movs + add under exec mask)
//      instead of a cnt==s compare-select chain (9 ops). Ballot checked per
//      sub-j, so cnt<=4 at every flush: the shift register never drops.
//  (c) flush walks a slot's 21-stage min/max network only if ANY lane holds
//      data in that slot (late-scan flushes carry 1-2 live slots).
// ---------------------------------------------------------------------------
__device__ inline unsigned umn(unsigned a, unsigned b) { return a < b ? a : b; }
__device__ inline unsigned umx(unsigned a, unsigned b) { return a > b ? a : b; }

__global__ __launch_bounds__(KTHR) void knn_kernel(const float* __restrict__ pos,
                                                   int* __restrict__ nbr) {
    __shared__ float smem[3 * PP];   // 48 KB arena
    float* sx = smem;
    float* sy = smem + PP;
    float* sz = smem + 2 * PP;

    int b = blockIdx.x >> 6;          // 64 blocks per graph
    int blkInGraph = blockIdx.x & 63;
    const float* gp = pos + (size_t)b * PP * 3;
    for (int i = threadIdx.x; i < PP; i += KTHR) {
        sx[i] = gp[i * 3 + 0];
        sy[i] = gp[i * 3 + 1];
        sz[i] = gp[i * 3 + 2];
    }
    __syncthreads();

    int eighth = threadIdx.x >> 6;        // 0..7 (one wave per eighth)
    int pt = threadIdx.x & (PTSBLK - 1);  // 0..63
    int li = blkInGraph * PTSBLK + pt;    // local point index in graph
    float px = sx[li], py = sy[li], pz = sz[li];

    unsigned bd[NSLOT];
#pragma unroll
    for (int k = 0; k < NSLOT; k++) bd[k] = SENT;
    unsigned worst = SENT;

    unsigned bufk[CAP];
    int cnt = 0;
#pragma unroll
    for (int s = 0; s < CAP; s++) bufk[s] = SENT;

    auto flush = [&]() {
#pragma unroll
        for (int s = 0; s < CAP; s++) {
            if (__any(bufk[s] != SENT)) {
                unsigned k = bufk[s];
#pragma unroll
                for (int i = 0; i < NSLOT; i++) {
                    unsigned lo = umn(k, bd[i]);   // v_min_u32
                    k = umx(k, bd[i]);             // v_max_u32
                    bd[i] = lo;
                }
            }
            bufk[s] = SENT;
        }
        cnt = 0;
        worst = bd[NSLOT - 1];
    };

    int jbeg = eighth * CHUNK;
    for (int jj = jbeg; jj < jbeg + CHUNK; jj += 4) {
        // wave-uniform candidate index -> b128 broadcast loads
        float4 xv = *(const float4*)(sx + jj);
        float4 yv = *(const float4*)(sy + jj);
        float4 zv = *(const float4*)(sz + jj);
        float xa[4] = {xv.x, xv.y, xv.z, xv.w};
        float ya[4] = {yv.x, yv.y, yv.z, yv.w};
        float za[4] = {zv.x, zv.y, zv.z, zv.w};
#pragma unroll
        for (int u = 0; u < 4; u++) {
            float dx = px - xa[u];
            float dy = py - ya[u];
            float dz = pz - za[u];
            float d = dx * dx;
            d = fmaf(dy, dy, d);
            d = fmaf(dz, dz, d);
            unsigned key = (__float_as_uint(d) & 0xFFFFF000u) | (unsigned)(jj + u);
            if (key < worst) {
                bufk[3] = bufk[2];
                bufk[2] = bufk[1];
                bufk[1] = bufk[0];
                bufk[0] = key;
                cnt++;
            }
            if (__any(cnt >= CAP)) flush();
        }
    }
    flush();

    // ---- 8-way merge of 21-long sorted lists per point via LDS ----
    // mk needs 8*64*21 = 10752 words <= 12288 arena words.
    __syncthreads();
    unsigned* mk = (unsigned*)smem;
#pragma unroll
    for (int k = 0; k < NSLOT; k++)
        mk[(eighth * PTSBLK + pt) * MPAD + k] = bd[k];
    __syncthreads();
    if (threadIdx.x < PTSBLK) {
        int p = threadIdx.x;
        const unsigned* base = &mk[p * MPAD];
        int cur[SPLIT];
#pragma unroll
        for (int q = 0; q < SPLIT; q++) cur[q] = 0;
        int gi = b * PP + blkInGraph * PTSBLK + p;
        // 21 picks; pick 0 is provably the self key (d=0 -> key=li < any
        // real key) and is skipped. Cursor reads stay within slots 0..20.
#pragma unroll
        for (int t = 0; t < NSLOT; t++) {
            unsigned v[SPLIT];
#pragma unroll
            for (int q = 0; q < SPLIT; q++)
                v[q] = base[q * PTSBLK * MPAD + cur[q]];
            unsigned m = v[0];
#pragma unroll
            for (int q = 1; q < SPLIT; q++) m = umn(m, v[q]);
            if (t > 0) nbr[gi * KNN + (t - 1)] = b * PP + (int)(m & 0xFFFu);
#pragma unroll
            for (int q = 0; q < SPLIT; q++) cur[q] += (v[q] == m);
        }
    }
}

// ---------------------------------------------------------------------------
// 3x3 helpers + power iteration (replicates reference arithmetic)
// ---------------------------------------------------------------------------
__device__ inline void mat3vec(const float M[9], const float v[3], float w[3]) {
    w[0] = M[0] * v[0] + M[1] * v[1] + M[2] * v[2];
    w[1] = M[3] * v[0] + M[4] * v[1] + M[5] * v[2];
    w[2] = M[6] * v[0] + M[7] * v[1] + M[8] * v[2];
}

__device__ inline float pi3(const float M[9], float v[3]) {
    v[0] = v[1] = v[2] = 0.57735026918962576f;  // 3^-0.5 as f32
#pragma unroll
    for (int it = 0; it < 5; ++it) {
        float w[3];
        mat3vec(M, v, w);
        float nrm = sqrtf(w[0] * w[0] + w[1] * w[1] + w[2] * w[2]) + 1e-12f;
        v[0] = w[0] / nrm;
        v[1] = w[1] / nrm;
        v[2] = w[2] / nrm;
    }
    float w[3];
    mat3vec(M, v, w);
    return v[0] * w[0] + v[1] * w[1] + v[2] * w[2];
}

// ---------------------------------------------------------------------------
// Kernel 2a: per-point eigen stage. 256 blocks x 128 threads (R6 used 128
// blocks = half the CUs idle on a latency-bound gather kernel).
// Writes v3 and prescaled rows R: spline coord v_c = c . R_c + 2.
// ---------------------------------------------------------------------------
__global__ __launch_bounds__(128) void eig_kernel(
    const float* __restrict__ pos, const int* __restrict__ nbr,
    float* __restrict__ Rbuf, float* __restrict__ v3out) {
    int n = blockIdx.x * 128 + threadIdx.x;
    float px = pos[n * 3 + 0], py = pos[n * 3 + 1], pz = pos[n * 3 + 2];

    float cx[KNN], cy[KNN], cz[KNN];
#pragma unroll
    for (int k = 0; k < KNN; k++) {
        int id = nbr[n * KNN + k];
        cx[k] = pos[id * 3 + 0] - px;
        cy[k] = pos[id * 3 + 1] - py;
        cz[k] = pos[id * 3 + 2] - pz;
    }

    float M[9] = {0.f, 0.f, 0.f, 0.f, 0.f, 0.f, 0.f, 0.f, 0.f};
#pragma unroll
    for (int m = 0; m < LCOV; m++) {
        M[0] += cx[m] * cx[m];
        M[1] += cx[m] * cy[m];
        M[2] += cx[m] * cz[m];
        M[4] += cy[m] * cy[m];
        M[5] += cy[m] * cz[m];
        M[8] += cz[m] * cz[m];
    }
    M[3] = M[1];
    M[6] = M[2];
    M[7] = M[5];

    float v1[3], v2[3], v3[3];
    float l1 = pi3(M, v1);
    float M2[9];
#pragma unroll
    for (int c = 0; c < 3; c++)
#pragma unroll
        for (int d = 0; d < 3; d++) M2[c * 3 + d] = M[c * 3 + d] - l1 * v1[c] * v1[d];
    pi3(M2, v2);
    v3[0] = v1[1] * v2[2] - v1[2] * v2[1];
    v3[1] = v1[2] * v2[0] - v1[0] * v2[2];
    v3[2] = v1[0] * v2[1] - v1[1] * v2[0];
    {
        float nrm = sqrtf(v3[0] * v3[0] + v3[1] * v3[1] + v3[2] * v3[2]) + 1e-12f;
        v3[0] /= nrm;
        v3[1] /= nrm;
        v3[2] /= nrm;
    }

    float ssum = 0.f, mx = 0.f;
#pragma unroll
    for (int k = 0; k < KNN; k++) {
        float d0 = cx[k] * v1[0] + cy[k] * v1[1] + cz[k] * v1[2];
        float d1 = cx[k] * v2[0] + cy[k] * v2[1] + cz[k] * v2[2];
        float d2 = cx[k] * v3[0] + cy[k] * v3[1] + cz[k] * v3[2];
        ssum += d2;
        mx = fmaxf(mx, fabsf(d0));
        mx = fmaxf(mx, fabsf(d1));
        mx = fmaxf(mx, fabsf(d2));
    }
    float sgn = (ssum > 0.f) ? 1.f : ((ssum < 0.f) ? -1.f : 0.f);

    float sc = 2.0f / mx;
    float* R = Rbuf + (size_t)n * 12;
    R[0] = v1[0] * sc;  R[1] = v1[1] * sc;  R[2] = v1[2] * sc;
    R[3] = v2[0] * sc;  R[4] = v2[1] * sc;  R[5] = v2[2] * sc;
    float s2 = sgn * sc;
    R[6] = v3[0] * s2;  R[7] = v3[1] * s2;  R[8] = v3[2] * s2;
    R[9] = 0.f; R[10] = 0.f; R[11] = 0.f;

    v3out[n * 3 + 0] = v3[0];
    v3out[n * 3 + 1] = v3[1];
    v3out[n * 3 + 2] = v3[2];
}

// ---------------------------------------------------------------------------
// Kernel 2b: spline conv. Block = 512 threads = 16 points.
// Phase 1 (320 threads = pt x k): basis weights; flat index packed into the
// low 7 mantissa bits of w (<=2^-16 perturbation) -> one LDS word per (k,s).
// Phase 2 (512 threads = pt x f): msg[f] = sum over 160 of w * sWt[f][flat].
// sWt transposed [f][flat] stride 125: within a 32-lane half (fixed pt),
// addresses are f*125+u -> gcd(125,32)=1 -> conflict-free; the two halves
// give at most 2-way aliasing (free per m136).
// ---------------------------------------------------------------------------
#define NPB 16
__global__ __launch_bounds__(512) void spline_kernel(
    const float* __restrict__ pos, const int* __restrict__ nbr,
    const float* __restrict__ Rbuf, const float* __restrict__ Wsp,
    const float* __restrict__ root, const float* __restrict__ bias,
    float* __restrict__ node) {
    __shared__ float sWt[FF * 125];          // [f][flat]
    __shared__ float wbuf[NPB * KNN * 8];    // packed w' per (pt,k,s)
    for (int i = threadIdx.x; i < FF * 125; i += 512) {
        int f = i / 125;
        int j = i - f * 125;
        sWt[i] = Wsp[j * FF + f];
    }

    int tid = threadIdx.x;
    if (tid < NPB * KNN) {              // 320 phase-1 threads
        int pt = tid / KNN;
        int k = tid - pt * KNN;
        int n = blockIdx.x * NPB + pt;
        const float4* Rv = (const float4*)(Rbuf + (size_t)n * 12);
        float4 r0 = Rv[0], r1 = Rv[1], r2 = Rv[2];
        float px = pos[n * 3 + 0], py = pos[n * 3 + 1], pz = pos[n * 3 + 2];
        int id = nbr[n * KNN + k];
        float cxx = pos[id * 3 + 0] - px;
        float cyy = pos[id * 3 + 1] - py;
        float czz = pos[id * 3 + 2] - pz;
        float v0 = fmaf(cxx, r0.x, fmaf(cyy, r0.y, fmaf(czz, r0.z, 2.0f)));
        float v1 = fmaf(cxx, r0.w, fmaf(cyy, r1.x, fmaf(czz, r1.y, 2.0f)));
        float v2 = fmaf(cxx, r1.z, fmaf(cyy, r1.w, fmaf(czz, r2.x, 2.0f)));
        float f0 = floorf(v0), f1 = floorf(v1), f2 = floorf(v2);
        float fr0 = v0 - f0, fr1 = v1 - f1, fr2 = v2 - f2;
        int fi0 = (int)f0, fi1 = (int)f1, fi2 = (int)f2;
        float* wdst = &wbuf[(pt * KNN + k) * 8];
#pragma unroll
        for (int s = 0; s < 8; s++) {
            int b0 = (s >> 2) & 1, b1 = (s >> 1) & 1, b2s = s & 1;
            int i0 = min(max(fi0 + b0, 0), KS - 1);
            int i1 = min(max(fi1 + b1, 0), KS - 1);
            int i2 = min(max(fi2 + b2s, 0), KS - 1);
            float w = (b0 ? fr0 : 1.f - fr0) * (b1 ? fr1 : 1.f - fr1) *
                      (b2s ? fr2 : 1.f - fr2);
            unsigned flat = (unsigned)((i0 * KS + i1) * KS + i2);
            wdst[s] = __uint_as_float((__float_as_uint(w) & ~127u) | flat);
        }
    }
    __syncthreads();

    // phase 2: thread = (pt, f)
    int pt = tid >> 5;
    int f = tid & 31;
    const float* wrow = &wbuf[pt * (KNN * 8)];
    const float* srow = &sWt[f * 125];
    float acc = 0.f;
#pragma unroll
    for (int k = 0; k < KNN; k++) {
        float4 wa = *(const float4*)&wrow[k * 8];
        float4 wb = *(const float4*)&wrow[k * 8 + 4];
        float wv[8] = {wa.x, wa.y, wa.z, wa.w, wb.x, wb.y, wb.z, wb.w};
#pragma unroll
        for (int s = 0; s < 8; s++) {
            unsigned u = __float_as_uint(wv[s]) & 127u;
            acc = fmaf(wv[s], srow[u], acc);
        }
    }
    int n = blockIdx.x * NPB + pt;
    node[(size_t)n * FF + f] = acc * (1.0f / KNN) + root[f] + bias[f];
}

// ---------------------------------------------------------------------------
// Kernel 3: batch-norm statistics (sum, sumsq per feature) via atomics.
// ---------------------------------------------------------------------------
__global__ __launch_bounds__(256) void bn_stats_kernel(const float* __restrict__ node,
                                                       float* __restrict__ sums) {
    __shared__ float ls[256];
    __shared__ float ls2[256];
    float s = 0.f, s2 = 0.f;
    int total = NPTS * FF;
    for (int i = blockIdx.x * 256 + threadIdx.x; i < total; i += gridDim.x * 256) {
        float x = node[i];
        s += x;
        s2 += x * x;
    }
    ls[threadIdx.x] = s;
    ls2[threadIdx.x] = s2;
    __syncthreads();
    if (threadIdx.x < FF) {
        float a = 0.f, b = 0.f;
        for (int t = threadIdx.x; t < 256; t += FF) {
            a += ls[t];
            b += ls2[t];
        }
        atomicAdd(&sums[threadIdx.x], a);
        atomicAdd(&sums[FF + threadIdx.x], b);
    }
}

// ---------------------------------------------------------------------------
// Kernel 4: apply BN, scale normal, sigmoid, reduce to ys (24, 32).
// ---------------------------------------------------------------------------
#define YSPLIT 8
#define YCHUNK (GROUPLEN / YSPLIT)   // 16384
__global__ __launch_bounds__(256) void ys_kernel(
    const float* __restrict__ node, const float* __restrict__ v3,
    const float* __restrict__ sums, const float* __restrict__ gamma,
    const float* __restrict__ beta, float* __restrict__ ys) {
    __shared__ float sa[FF], sb[FF];
    if (threadIdx.x < FF) {
        int f = threadIdx.x;
        float mu = sums[f] * (1.0f / NPTS);
        float var = sums[FF + f] * (1.0f / NPTS) - mu * mu;
        float inv = 1.0f / sqrtf(var + 1e-5f);
        sa[f] = gamma[f] * inv;
        sb[f] = beta[f] - gamma[f] * inv * mu;
    }
    __syncthreads();

    int g = blockIdx.x >> 3;
    int sub = blockIdx.x & 7;
    float acc = 0.f;
    int ibeg = sub * YCHUNK + threadIdx.x;
    int iend = (sub + 1) * YCHUNK;
    for (int i = ibeg; i < iend; i += 256) {
        int t = g * GROUPLEN + i;
        int n = t / 96;
        int r = t - n * 96;
        int f = r / 3;
        int c = r - f * 3;
        float xb = sa[f] * node[(size_t)n * FF + f] + sb[f];
        float val = xb * v3[n * 3 + c];
        acc += 1.0f / (1.0f + expf(-val));
    }
    __shared__ float red[256];
    red[threadIdx.x] = acc;
    __syncthreads();
    if (threadIdx.x < FF) {
        float s = 0.f;
        for (int t = threadIdx.x; t < 256; t += FF) s += red[t];
        atomicAdd(&ys[g * FF + threadIdx.x], s * (1.0f / PP));
    }
}

// ---------------------------------------------------------------------------
// Kernel 5: tiny MLP head: elu(ys@W1+b1) @ W2 + b2 -> log_softmax. 1 block/row.
// ---------------------------------------------------------------------------
__global__ __launch_bounds__(256) void head_kernel(
    const float* __restrict__ ys, const float* __restrict__ W1,
    const float* __restrict__ b1, const float* __restrict__ W2,
    const float* __restrict__ b2, float* __restrict__ out) {
    int g = blockIdx.x;
    __shared__ float syr[FF];
    __shared__ float h[256];
    __shared__ float logits[NCLS];
    __shared__ float mstat[2];
    if (threadIdx.x < FF) syr[threadIdx.x] = ys[g * FF + threadIdx.x];
    __syncthreads();
    int j = threadIdx.x;
    float acc = b1[j];
#pragma unroll
    for (int f = 0; f < FF; f++) acc += syr[f] * W1[f * 256 + j];
    h[j] = acc > 0.f ? acc : expm1f(acc);
    __syncthreads();
    if (j < NCLS) {
        float l = b2[j];
        for (int q = 0; q < 256; q++) l += h[q] * W2[q * NCLS + j];
        logits[j] = l;
    }
    __syncthreads();
    if (j == 0) {
        float m = -INFINITY;
        for (int o = 0; o < NCLS; o++) m = fmaxf(m, logits[o]);
        float s = 0.f;
        for (int o = 0; o < NCLS; o++) s += expf(logits[o] - m);
        mstat[0] = m;
        mstat[1] = logf(s);
    }
    __syncthreads();
    if (j < NCLS) out[g * NCLS + j] = logits[j] - mstat[0] - mstat[1];
}

// ---------------------------------------------------------------------------
extern "C" void kernel_launch(void* const* d_in, const int* in_sizes, int n_in,
                              void* d_out, int out_size, void* d_ws, size_t ws_size,
                              hipStream_t stream) {
    const float* pos   = (const float*)d_in[0];
    const float* Wsp   = (const float*)d_in[1];
    const float* root  = (const float*)d_in[2];
    const float* bias  = (const float*)d_in[3];
    const float* gamma = (const float*)d_in[4];
    const float* beta  = (const float*)d_in[5];
    const float* W1    = (const float*)d_in[6];
    const float* b1    = (const float*)d_in[7];
    const float* W2    = (const float*)d_in[8];
    const float* b2    = (const float*)d_in[9];
    float* out = (float*)d_out;

    char* ws = (char*)d_ws;
    int* nbr    = (int*)(ws);                      // 32768*20*4   = 2621440 B
    float* node = (float*)(ws + 2621440);          // 32768*32*4   = 4194304 B
    float* v3   = (float*)(ws + 6815744);          // 32768*3*4    = 393216 B
    float* sums = (float*)(ws + 7208960);          // 64*4         = 256 B
    float* ys   = (float*)(ws + 7209216);          // 24*32*4      = 3072 B
    float* Rbuf = (float*)(ws + 7212288);          // 32768*12*4   = 1572864 B
                                                   // total 8785152 B

    // zero sums (256 B) + ys (3072 B) in one contiguous memset
    hipMemsetAsync(sums, 0, 3328, stream);

    knn_kernel<<<512, KTHR, 0, stream>>>(pos, nbr);
    eig_kernel<<<256, 128, 0, stream>>>(pos, nbr, Rbuf, v3);
    spline_kernel<<<NPTS / NPB, 512, 0, stream>>>(pos, nbr, Rbuf, Wsp, root, bias, node);
    bn_stats_kernel<<<128, 256, 0, stream>>>(node, sums);
    ys_kernel<<<NGROUP * YSPLIT, 256, 0, stream>>>(node, v3, sums, gamma, beta, ys);
    head_kernel<<<NGROUP, 256, 0, stream>>>(ys, W1, b1, W2, b2, out);
}